// Round 4
// baseline (1435.126 us; speedup 1.0000x reference)
//
#include <hip/hip_runtime.h>

#define BB 2048
#define IMG 784
#define HWD 28
#define C1 32
#define C2 64
#define PP 169
#define PD 13
#define F3 10816
#define N3 2048
#define K3W 169
#define K4W 32
#define NOUT 10
#define CONV 27          // pooled-used conv2 output region is 27x27
#define PADW 30          // padded image row stride (cols -1..28)
#define OCCHUNK 8        // ocs per conv2pool scratch phase
#define SCRS 736         // 729 padded

__device__ __forceinline__ float ap2mag(float c) {
    // 2^round(log2(max(|c|,1e-38)))  (round half to even, like jnp.round)
    float a = fmaxf(fabsf(c), 1e-38f);
    return exp2f(rintf(log2f(a)));
}

// ---------------- conv1 (fp32 x, binarized weights) ----------------
// 8 samples per block (256 blocks): 8x fewer same-address double atomics.
__global__ __launch_bounds__(256) void conv1_stats(const float* __restrict__ x, const float* __restrict__ w1,
                            const float* __restrict__ cb1, const float* __restrict__ meanIn,
                            double* __restrict__ outSum, int pass) {
    __shared__ float xs[IMG];
    __shared__ float ws[C1 * 9];
    __shared__ float red[256];
    int tid = threadIdx.x;
    for (int i = tid; i < C1 * 9; i += 256) ws[i] = (w1[i] >= 0.f) ? 1.f : -1.f;
    __syncthreads();
    int ch = tid & 31, slice = tid >> 5;
    float b = cb1[ch];
    float m = pass ? meanIn[ch] : 0.f;
    float k0 = ws[ch * 9 + 0], k1 = ws[ch * 9 + 1], k2 = ws[ch * 9 + 2];
    float k3 = ws[ch * 9 + 3], k4 = ws[ch * 9 + 4], k5 = ws[ch * 9 + 5];
    float k6 = ws[ch * 9 + 6], k7 = ws[ch * 9 + 7], k8 = ws[ch * 9 + 8];
    float acc = 0.f;
    for (int ns = 0; ns < 8; ns++) {
        int n = blockIdx.x * 8 + ns;
        __syncthreads();
        for (int i = tid; i < IMG; i += 256) xs[i] = x[n * IMG + i];
        __syncthreads();
        for (int p = slice; p < IMG; p += 8) {
            int py = p / HWD, px = p - py * HWD;
            bool tp = py > 0, bo = py < HWD - 1, lf = px > 0, rt = px < HWD - 1;
            const float* c0 = &xs[p];
            float s = c0[0] * k4;
            if (tp) {
                s += c0[-HWD] * k1;
                if (lf) s += c0[-HWD - 1] * k0;
                if (rt) s += c0[-HWD + 1] * k2;
            }
            if (lf) s += c0[-1] * k3;
            if (rt) s += c0[1] * k5;
            if (bo) {
                s += c0[HWD] * k7;
                if (lf) s += c0[HWD - 1] * k6;
                if (rt) s += c0[HWD + 1] * k8;
            }
            float v = fmaxf(s + b, 0.f);
            if (pass == 0) acc += v;
            else { float c = v - m; acc += fabsf(c) * ap2mag(c); }
        }
    }
    red[tid] = acc;
    __syncthreads();
    if (tid < C1) {
        float t = 0.f;
        for (int sl = 0; sl < 8; sl++) t += red[sl * 32 + tid];
        atomicAdd(&outSum[tid], (double)t);
    }
}

// binarize(shift_bn(relu(conv1))) -> 32 channel bits packed per pixel via __ballot.
__global__ void conv1_pack(const float* __restrict__ x, const float* __restrict__ w1,
                           const float* __restrict__ cb1, const float* __restrict__ mean1,
                           const float* __restrict__ scale1, const float* __restrict__ beta1,
                           unsigned int* __restrict__ s1p) {
    __shared__ float xs[IMG];
    __shared__ float ws[C1 * 9];
    __shared__ unsigned int pbits[IMG];
    int n = blockIdx.x, tid = threadIdx.x;
    for (int i = tid; i < IMG; i += 256) xs[i] = x[n * IMG + i];
    for (int i = tid; i < C1 * 9; i += 256) ws[i] = (w1[i] >= 0.f) ? 1.f : -1.f;
    __syncthreads();
    int ch = tid & 31, slice = tid >> 5;
    float b = cb1[ch];
    float m = mean1[ch];
    float sc = scale1[ch];
    float bt = beta1[ch];
    float k0 = ws[ch * 9 + 0], k1 = ws[ch * 9 + 1], k2 = ws[ch * 9 + 2];
    float k3 = ws[ch * 9 + 3], k4 = ws[ch * 9 + 4], k5 = ws[ch * 9 + 5];
    float k6 = ws[ch * 9 + 6], k7 = ws[ch * 9 + 7], k8 = ws[ch * 9 + 8];
    int half = tid & 63;  // 0 or 32 writes
    for (int p = slice; p < IMG; p += 8) {
        int py = p / HWD, px = p - py * HWD;
        bool tp = py > 0, bo = py < HWD - 1, lf = px > 0, rt = px < HWD - 1;
        const float* c0 = &xs[p];
        float s = c0[0] * k4;
        if (tp) {
            s += c0[-HWD] * k1;
            if (lf) s += c0[-HWD - 1] * k0;
            if (rt) s += c0[-HWD + 1] * k2;
        }
        if (lf) s += c0[-1] * k3;
        if (rt) s += c0[1] * k5;
        if (bo) {
            s += c0[HWD] * k7;
            if (lf) s += c0[HWD - 1] * k6;
            if (rt) s += c0[HWD + 1] * k8;
        }
        float v = fmaxf(s + b, 0.f);
        float val = sc * (v - m) + bt;
        unsigned long long mask = __ballot(val >= 0.f);
        if (half == 0) pbits[p] = (unsigned int)mask;
        else if (half == 32) pbits[p] = (unsigned int)(mask >> 32);
    }
    __syncthreads();
    for (int i = tid; i < IMG; i += 256) s1p[n * IMG + i] = pbits[i];
}

// ---------------- conv2 weight packing ----------------
__global__ void pack_w2(const float* __restrict__ w2, unsigned int* __restrict__ w2p) {
    int t = blockIdx.x * blockDim.x + threadIdx.x;
    if (t >= C2 * 9) return;
    int oc = t / 9, k = t % 9;
    unsigned int bits = 0;
    for (int ic = 0; ic < C1; ic++)
        bits |= (w2[oc * 288 + ic * 9 + k] >= 0.f ? 1u : 0u) << ic;
    w2p[t] = bits;
}

// ---------------- fused conv2 + maxpool3s2, register-window version ----------------
// R3 post-mortem: tap loop was ds_read-bound (~1 LDS read per tap). Fix: each
// thread loads its pixels' 9-word windows into REGISTERS once (zero-padded LDS
// image), then loops all 64 ocs with weights as SCALAR loads (uniform index ->
// s_load; v_xor takes the SGPR operand). Inner loop: 0 LDS reads per tap.
// Zero-pad correction: pad word 0 contributes popc(w_k) to s, so
// conv = 32*nvalid - 2*s + 2*sum_pad popc(w_k) -> per-oc scalar consts ct/cl/cc.
__global__ __launch_bounds__(256) void conv2pool(const unsigned int* __restrict__ s1p,
                                                 const unsigned int* __restrict__ w2p,
                                                 short* __restrict__ p2i) {
    __shared__ unsigned int spad[29 * PADW];   // rows -1..27, cols -1..28 (3.5 KB)
    __shared__ short scr[OCCHUNK * SCRS];      // 11.8 KB
    int n = blockIdx.x, tid = threadIdx.x;
    for (int i = tid; i < 29 * PADW; i += 256) {
        int r = i / PADW, c = i - r * PADW;
        unsigned int v = 0;
        if (r >= 1 && c >= 1 && c <= 28) v = s1p[n * IMG + (r - 1) * HWD + (c - 1)];
        spad[i] = v;
    }
    __syncthreads();
    // pixels p = tid, tid+256, tid+512 (third only for tid<217); 729 total
    unsigned int win[3][9];
    bool top_[3], left_[3];
    bool act2 = (tid + 512) < CONV * CONV;
#pragma unroll
    for (int pi = 0; pi < 3; pi++) {
        int p = tid + pi * 256;
        if (p >= CONV * CONV) p = 0;  // inactive lanes load safe dummy
        int y = p / CONV, xx = p - y * CONV;
        top_[pi] = (y == 0);
        left_[pi] = (xx == 0);
        const unsigned int* bp = &spad[y * PADW + xx];
#pragma unroll
        for (int ky = 0; ky < 3; ky++)
#pragma unroll
            for (int kx = 0; kx < 3; kx++)
                win[pi][ky * 3 + kx] = bp[ky * PADW + kx];
    }
    for (int base = 0; base < C2; base += OCCHUNK) {
        for (int ol = 0; ol < OCCHUNK; ol++) {
            int oc = base + ol;
            unsigned int w0 = w2p[oc * 9 + 0], w1 = w2p[oc * 9 + 1], w2 = w2p[oc * 9 + 2];
            unsigned int w3 = w2p[oc * 9 + 3], w4 = w2p[oc * 9 + 4], w5 = w2p[oc * 9 + 5];
            unsigned int w6 = w2p[oc * 9 + 6], w7 = w2p[oc * 9 + 7], w8 = w2p[oc * 9 + 8];
            int p0 = __popc(w0), p1 = __popc(w1), p2 = __popc(w2);
            int p3 = __popc(w3), p6 = __popc(w6);
            int ct = 192 + 2 * (p0 + p1 + p2);
            int cl = 192 + 2 * (p0 + p3 + p6);
            int cc = 128 + 2 * (p0 + p1 + p2 + p3 + p6);
#pragma unroll
            for (int pi = 0; pi < 3; pi++) {
                int s = __popc(win[pi][0] ^ w0) + __popc(win[pi][1] ^ w1) + __popc(win[pi][2] ^ w2)
                      + __popc(win[pi][3] ^ w3) + __popc(win[pi][4] ^ w4) + __popc(win[pi][5] ^ w5)
                      + __popc(win[pi][6] ^ w6) + __popc(win[pi][7] ^ w7) + __popc(win[pi][8] ^ w8);
                int off = top_[pi] ? (left_[pi] ? cc : ct) : (left_[pi] ? cl : 288);
                if (pi < 2 || act2) scr[ol * SCRS + tid + pi * 256] = (short)(off - 2 * s);
            }
        }
        __syncthreads();
        for (int q = tid; q < OCCHUNK * PP; q += 256) {
            int ol = q / PP, pix = q - ol * PP;
            int py = pix / PD, px = pix - py * PD;
            const short* r = &scr[ol * SCRS + (2 * py) * CONV + 2 * px];
            int m0 = max(max((int)r[0], (int)r[1]), (int)r[2]);
            int m1 = max(max((int)r[CONV], (int)r[CONV + 1]), (int)r[CONV + 2]);
            int m2 = max(max((int)r[2 * CONV], (int)r[2 * CONV + 1]), (int)r[2 * CONV + 2]);
            p2i[n * F3 + (base + ol) * PP + pix] = (short)max(max(m0, m1), m2);
        }
        __syncthreads();
    }
}

// ---------------- stats over pooled layer-2 ----------------
// Coalesced (lane -> p), 8 samples per block, wave owns 16 chs -> shuffle-reduce.
__global__ __launch_bounds__(256) void p2_stats(const short* __restrict__ p2i, const float* __restrict__ cb2,
                         const float* __restrict__ meanIn, double* __restrict__ outSum, int pass) {
    int tid = threadIdx.x, lane = tid & 63, wv = tid >> 6;
    float accs[16];
#pragma unroll
    for (int i = 0; i < 16; i++) accs[i] = 0.f;
    for (int ns = 0; ns < 8; ns++) {
        const short* rowb = p2i + (size_t)(blockIdx.x * 8 + ns) * F3;
        for (int i = 0; i < 16; i++) {
            int ch = wv * 16 + i;
            const short* row = rowb + ch * PP;
            float b = cb2[ch];
            float m = pass ? meanIn[ch] : 0.f;
            float a = 0.f;
            for (int p = lane; p < PP; p += 64) {
                float v = fmaxf((float)row[p] + b, 0.f);
                if (pass == 0) a += v;
                else { float c = v - m; a += fabsf(c) * ap2mag(c); }
            }
            accs[i] += a;
        }
    }
#pragma unroll
    for (int i = 0; i < 16; i++) {
        float a = accs[i];
        for (int off = 32; off; off >>= 1) a += __shfl_down(a, off);
        if (lane == 0) atomicAdd(&outSum[wv * 16 + i], (double)a);
    }
}

// binarize layer-2 -> packed u64 rows; grid-stride over wave-words.
__global__ void p2_pack(const short* __restrict__ p2i, const float* __restrict__ cb2,
                        const float* __restrict__ mean2, const float* __restrict__ scale2,
                        const float* __restrict__ beta2, unsigned long long* __restrict__ hp3) {
    int lane = threadIdx.x & 63;
    int wid = (blockIdx.x * blockDim.x + threadIdx.x) >> 6;
    int nw = (gridDim.x * blockDim.x) >> 6;
    for (int w = wid; w < BB * K3W; w += nw) {
        int n = w / K3W, j = w - n * K3W;
        int f = j * 64 + lane;
        int oc = f / PP;
        float v = fmaxf((float)p2i[n * F3 + f] + cb2[oc], 0.f);
        float val = scale2[oc] * (v - mean2[oc]) + beta2[oc];
        unsigned long long mask = __ballot(val >= 0.f);
        if (lane == 0) hp3[w] = mask;
    }
}

__global__ void w3_pack(const float* __restrict__ w3, unsigned long long* __restrict__ wp3) {
    int lane = threadIdx.x & 63;
    int wid = (blockIdx.x * blockDim.x + threadIdx.x) >> 6;
    int nw = (gridDim.x * blockDim.x) >> 6;
    for (int w = wid; w < N3 * K3W; w += nw) {
        int nn = w / K3W, j = w - nn * K3W;
        float wv = w3[(size_t)nn * F3 + j * 64 + lane];
        unsigned long long mask = __ballot(wv >= 0.f);
        if (lane == 0) wp3[w] = mask;
    }
}

// ---------------- lin3: XNOR-popcount GEMM, 64x64 tile, 4x4 per thread ----------------
__global__ __launch_bounds__(256) void lin3_gemm(const unsigned long long* __restrict__ hp3,
                                                 const unsigned long long* __restrict__ wp3,
                                                 const float* __restrict__ b3l,
                                                 float* __restrict__ h3) {
    __shared__ unsigned long long aT[64][9];
    __shared__ unsigned long long bT[64][9];
    int tx = threadIdx.x & 15, ty = threadIdx.x >> 4;
    int m0 = blockIdx.y * 64, n0 = blockIdx.x * 64;
    int s[4][4];
#pragma unroll
    for (int i = 0; i < 4; i++)
#pragma unroll
        for (int j = 0; j < 4; j++) s[i][j] = 0;
    for (int k0 = 0; k0 < K3W; k0 += 8) {
        for (int t = threadIdx.x; t < 512; t += 256) {
            int r = t >> 3, kk = t & 7;
            int k = k0 + kk;
            aT[r][kk] = (k < K3W) ? hp3[(m0 + r) * K3W + k] : 0ULL;
            bT[r][kk] = (k < K3W) ? wp3[(n0 + r) * K3W + k] : 0ULL;
        }
        __syncthreads();
#pragma unroll
        for (int kk = 0; kk < 8; kk++) {
            unsigned long long a[4], b[4];
#pragma unroll
            for (int i = 0; i < 4; i++) a[i] = aT[ty * 4 + i][kk];
#pragma unroll
            for (int j = 0; j < 4; j++) b[j] = bT[tx * 4 + j][kk];
#pragma unroll
            for (int i = 0; i < 4; i++)
#pragma unroll
                for (int j = 0; j < 4; j++) s[i][j] += __popcll(a[i] ^ b[j]);
        }
        __syncthreads();
    }
#pragma unroll
    for (int i = 0; i < 4; i++) {
        int m = m0 + ty * 4 + i;
#pragma unroll
        for (int j = 0; j < 4; j++) {
            int nn = n0 + tx * 4 + j;
            float v = fmaxf((float)(F3 - 2 * s[i][j]) + b3l[nn], 0.f);
            h3[(size_t)m * N3 + nn] = v;
        }
    }
}

// ---------------- stats over h3 (per feature, across batch) ----------------
__global__ void h3_stats(const float* __restrict__ h3, const float* __restrict__ meanIn,
                         double* __restrict__ outSum, int pass) {
    int nn = blockIdx.x * 256 + threadIdx.x;
    int m0 = blockIdx.y * 128;
    float m = pass ? meanIn[nn] : 0.f;
    float acc = 0.f;
    for (int mm = m0; mm < m0 + 128; mm++) {
        float v = h3[(size_t)mm * N3 + nn];
        if (pass == 0) acc += v;
        else { float c = v - m; acc += fabsf(c) * ap2mag(c); }
    }
    atomicAdd(&outSum[nn], (double)acc);
}

__global__ void h3_pack(const float* __restrict__ h3, const float* __restrict__ mean3,
                        const float* __restrict__ scale3, const float* __restrict__ beta3,
                        unsigned long long* __restrict__ h4p) {
    int lane = threadIdx.x & 63;
    int wid = (blockIdx.x * blockDim.x + threadIdx.x) >> 6;
    int nw = (gridDim.x * blockDim.x) >> 6;
    for (int w = wid; w < BB * K4W; w += nw) {
        int m = w / K4W, j = w - m * K4W;
        int f = j * 64 + lane;
        float v = h3[(size_t)m * N3 + f];
        float val = scale3[f] * (v - mean3[f]) + beta3[f];
        unsigned long long mask = __ballot(val >= 0.f);
        if (lane == 0) h4p[w] = mask;
    }
}

__global__ void w4_pack(const float* __restrict__ w4, unsigned long long* __restrict__ wp4) {
    int gw = (blockIdx.x * blockDim.x + threadIdx.x) >> 6;
    int lane = threadIdx.x & 63;
    if (gw >= NOUT * K4W) return;
    int o = gw / K4W, j = gw % K4W;
    float w = w4[o * N3 + j * 64 + lane];
    unsigned long long mask = __ballot(w >= 0.f);
    if (lane == 0) wp4[o * K4W + j] = mask;
}

// one thread per (m,o); weights in LDS with stride 33 (pad breaks 10-way conflict)
__global__ __launch_bounds__(256) void lin4_out(const unsigned long long* __restrict__ h4p,
                                                const unsigned long long* __restrict__ wp4,
                                                const float* __restrict__ b4,
                                                float* __restrict__ out) {
    __shared__ unsigned long long w[NOUT * 33];
    int tid = threadIdx.x;
    for (int i = tid; i < NOUT * K4W; i += 256) w[(i / K4W) * 33 + (i % K4W)] = wp4[i];
    __syncthreads();
    int g = blockIdx.x * 256 + tid;  // 80 blocks * 256 = 20480 exactly
    int m = g / NOUT, o = g - m * NOUT;
    const unsigned long long* h = &h4p[(size_t)m * K4W];
    int c = 0;
#pragma unroll
    for (int k = 0; k < K4W; k++) c += __popcll(h[k] ^ w[o * 33 + k]);
    out[g] = (float)(N3 - 2 * c) + b4[o];
}

// ---------------- small finalize kernels ----------------
__global__ void finalize_mean(const double* __restrict__ sumd, float* __restrict__ meanOut,
                              int n, double count) {
    int i = blockIdx.x * blockDim.x + threadIdx.x;
    if (i < n) meanOut[i] = (float)(sumd[i] / count);
}

__global__ void finalize_scale(const double* __restrict__ vard, const float* __restrict__ g,
                               float* __restrict__ scaleOut, int n, double count) {
    int i = blockIdx.x * blockDim.x + threadIdx.x;
    if (i >= n) return;
    float var = (float)(vard[i] / count);
    float t = var + 1e-4f;
    float inv = 1.0f / sqrtf(t);
    double p = exp2(rint(log2((double)inv)));
    float gg = g[i];
    float ap2g;
    if (gg == 0.f) ap2g = 0.f;
    else {
        double ag = fabs((double)gg);
        if (ag < 1e-38) ag = 1e-38;
        ap2g = (float)exp2(rint(log2(ag)));
        if (gg < 0.f) ap2g = -ap2g;
    }
    scaleOut[i] = ap2g * (float)p;
}

extern "C" void kernel_launch(void* const* d_in, const int* in_sizes, int n_in,
                              void* d_out, int out_size, void* d_ws, size_t ws_size,
                              hipStream_t stream) {
    const float* x   = (const float*)d_in[0];
    const float* w1  = (const float*)d_in[1];
    const float* cb1 = (const float*)d_in[2];
    const float* g1  = (const float*)d_in[3];
    const float* bt1 = (const float*)d_in[4];
    const float* w2  = (const float*)d_in[5];
    const float* cb2 = (const float*)d_in[6];
    const float* g2  = (const float*)d_in[7];
    const float* bt2 = (const float*)d_in[8];
    const float* w3  = (const float*)d_in[9];
    const float* b3l = (const float*)d_in[10];
    const float* g3  = (const float*)d_in[11];
    const float* bt3 = (const float*)d_in[12];
    const float* w4  = (const float*)d_in[13];
    const float* b4l = (const float*)d_in[14];
    float* out = (float*)d_out;

    char* base = (char*)d_ws;
    size_t off = 0;
    auto carve = [&](size_t bytes) { char* p = base + off; off = (off + bytes + 255) & ~(size_t)255; return p; };
    unsigned int* s1p       = (unsigned int*)carve((size_t)BB * IMG * 4);
    short* p2i              = (short*)carve((size_t)BB * C2 * PP * 2);
    unsigned long long* hp3 = (unsigned long long*)carve((size_t)BB * K3W * 8);
    unsigned long long* wp3 = (unsigned long long*)carve((size_t)N3 * K3W * 8);
    float* h3               = (float*)carve((size_t)BB * N3 * 4);
    unsigned long long* h4p = (unsigned long long*)carve((size_t)BB * K4W * 8);
    unsigned long long* wp4 = (unsigned long long*)carve((size_t)NOUT * K4W * 8);
    unsigned int* w2p       = (unsigned int*)carve((size_t)C2 * 9 * 4);
    double* sums            = (double*)carve((size_t)(32 + 32 + 64 + 64 + 2048 + 2048) * 8);
    double* sum1d = sums;        // 32
    double* var1d = sums + 32;   // 32
    double* sum2d = sums + 64;   // 64
    double* var2d = sums + 128;  // 64
    double* sum3d = sums + 192;  // 2048
    double* var3d = sums + 2240; // 2048
    float* fstats           = (float*)carve((size_t)(32 + 32 + 64 + 64 + 2048 + 2048) * 4);
    float* mean1 = fstats;          float* scale1 = fstats + 32;
    float* mean2 = fstats + 64;     float* scale2 = fstats + 128;
    float* mean3 = fstats + 192;    float* scale3 = fstats + 2240;

    hipMemsetAsync(sums, 0, (size_t)(32 + 32 + 64 + 64 + 2048 + 2048) * 8, stream);

    // layer 1
    conv1_stats<<<256, 256, 0, stream>>>(x, w1, cb1, mean1, sum1d, 0);
    finalize_mean<<<1, 64, 0, stream>>>(sum1d, mean1, 32, (double)BB * IMG);
    conv1_stats<<<256, 256, 0, stream>>>(x, w1, cb1, mean1, var1d, 1);
    finalize_scale<<<1, 64, 0, stream>>>(var1d, g1, scale1, 32, (double)BB * IMG);
    conv1_pack<<<BB, 256, 0, stream>>>(x, w1, cb1, mean1, scale1, bt1, s1p);

    // layer 2
    pack_w2<<<1, 576, 0, stream>>>(w2, w2p);
    conv2pool<<<BB, 256, 0, stream>>>(s1p, w2p, p2i);
    p2_stats<<<256, 256, 0, stream>>>(p2i, cb2, mean2, sum2d, 0);
    finalize_mean<<<1, 64, 0, stream>>>(sum2d, mean2, 64, (double)BB * PP);
    p2_stats<<<256, 256, 0, stream>>>(p2i, cb2, mean2, var2d, 1);
    finalize_scale<<<1, 64, 0, stream>>>(var2d, g2, scale2, 64, (double)BB * PP);
    p2_pack<<<1024, 256, 0, stream>>>(p2i, cb2, mean2, scale2, bt2, hp3);

    // lin3
    w3_pack<<<2048, 256, 0, stream>>>(w3, wp3);
    lin3_gemm<<<dim3(32, 32), 256, 0, stream>>>(hp3, wp3, b3l, h3);
    h3_stats<<<dim3(8, 16), 256, 0, stream>>>(h3, mean3, sum3d, 0);
    finalize_mean<<<8, 256, 0, stream>>>(sum3d, mean3, 2048, (double)BB);
    h3_stats<<<dim3(8, 16), 256, 0, stream>>>(h3, mean3, var3d, 1);
    finalize_scale<<<8, 256, 0, stream>>>(var3d, g3, scale3, 2048, (double)BB);
    h3_pack<<<256, 256, 0, stream>>>(h3, mean3, scale3, bt3, h4p);

    // lin4
    w4_pack<<<(NOUT * K4W + 3) / 4, 256, 0, stream>>>(w4, wp4);
    lin4_out<<<80, 256, 0, stream>>>(h4p, wp4, b4l, out);

    (void)in_sizes; (void)n_in; (void)out_size; (void)ws_size;
}

// Round 5
// 724.130 us; speedup vs baseline: 1.9819x; 1.9819x over previous
//
#include <hip/hip_runtime.h>

#define BB 2048
#define IMG 784
#define HWD 28
#define C1 32
#define C2 64
#define PP 169
#define PD 13
#define F3 10816
#define N3 2048
#define K3W 169
#define K4W 32
#define NOUT 10
#define CONV 27          // pooled-used conv2 output region is 27x27
#define PADW 30          // padded image row stride (cols -1..28)
#define OCCHUNK 8        // ocs per conv2pool scratch phase
#define SCRS 736         // 729 padded

__device__ __forceinline__ float ap2mag(float c) {
    // 2^round(log2(max(|c|,1e-38)))  (round half to even, like jnp.round)
    float a = fmaxf(fabsf(c), 1e-38f);
    return exp2f(rintf(log2f(a)));
}

// ---------------- weight binarization ----------------
__global__ void pack_w1(const float* __restrict__ w1, float* __restrict__ w1b) {
    int i = threadIdx.x;
    if (i < C1 * 9) w1b[i] = (w1[i] >= 0.f) ? 1.f : -1.f;
}

// ---------------- conv1 (fp32 x, binarized weights), register-window ----------------
// 2048 blocks (R4 lesson: grid shrink to 256 collapsed occupancy to 12% -> 310us).
// Thread owns 4 contiguous pixels of one row (28 = 7*4), 3x6 window in 18 regs
// from zero-padded LDS image; 32-ch loop with UNIFORM scalar weight loads ->
// 0 LDS reads per tap (the conv2pool-R4 structure that worked).
__global__ __launch_bounds__(256) void conv1_stats(const float* __restrict__ x,
                            const float* __restrict__ w1b,
                            const float* __restrict__ cb1, const float* __restrict__ meanIn,
                            float* __restrict__ part, int pass) {
    __shared__ float xs[30 * PADW];
    __shared__ float red[4 * C1];
    int n = blockIdx.x, tid = threadIdx.x;
    for (int i = tid; i < 30 * PADW; i += 256) {
        int r = i / PADW - 1, c = i % PADW - 1;
        float v = 0.f;
        if (r >= 0 && r < HWD && c >= 0 && c < HWD) v = x[n * IMG + r * HWD + c];
        xs[i] = v;
    }
    __syncthreads();
    bool act = tid < 196;
    int r = tid / 7, c0 = (tid % 7) * 4;
    float win[18];
#pragma unroll
    for (int k = 0; k < 18; k++) win[k] = 0.f;
    if (act) {
#pragma unroll
        for (int ry = 0; ry < 3; ry++)
#pragma unroll
            for (int cx = 0; cx < 6; cx++)
                win[ry * 6 + cx] = xs[(r + ry) * PADW + c0 + cx];
    }
    float acc[C1];
#pragma unroll
    for (int ch = 0; ch < C1; ch++) acc[ch] = 0.f;
    if (act) {
#pragma unroll
        for (int ch = 0; ch < C1; ch++) {
            float k0 = w1b[ch * 9 + 0], k1 = w1b[ch * 9 + 1], k2 = w1b[ch * 9 + 2];
            float k3 = w1b[ch * 9 + 3], k4 = w1b[ch * 9 + 4], k5 = w1b[ch * 9 + 5];
            float k6 = w1b[ch * 9 + 6], k7 = w1b[ch * 9 + 7], k8 = w1b[ch * 9 + 8];
            float b = cb1[ch];
            float m = pass ? meanIn[ch] : 0.f;
            float a = 0.f;
#pragma unroll
            for (int px = 0; px < 4; px++) {
                float s = win[px] * k0 + win[px + 1] * k1 + win[px + 2] * k2
                        + win[6 + px] * k3 + win[7 + px] * k4 + win[8 + px] * k5
                        + win[12 + px] * k6 + win[13 + px] * k7 + win[14 + px] * k8;
                float v = fmaxf(s + b, 0.f);
                if (pass == 0) a += v;
                else { float c = v - m; a += fabsf(c) * ap2mag(c); }
            }
            acc[ch] = a;
        }
    }
    int lane = tid & 63, wv = tid >> 6;
#pragma unroll
    for (int ch = 0; ch < C1; ch++) {
        float a = acc[ch];
        for (int off = 32; off; off >>= 1) a += __shfl_down(a, off);
        if (lane == 0) red[wv * C1 + ch] = a;
    }
    __syncthreads();
    if (tid < C1) part[n * C1 + tid] = red[tid] + red[C1 + tid] + red[2 * C1 + tid] + red[3 * C1 + tid];
}

// binarize(shift_bn(relu(conv1))) -> 32 channel bits per pixel, built in registers,
// stored as one aligned uint4 per thread (no ballot, no LDS round-trip).
__global__ __launch_bounds__(256) void conv1_pack(const float* __restrict__ x,
                           const float* __restrict__ w1b,
                           const float* __restrict__ cb1, const float* __restrict__ mean1,
                           const float* __restrict__ scale1, const float* __restrict__ beta1,
                           unsigned int* __restrict__ s1p) {
    __shared__ float xs[30 * PADW];
    int n = blockIdx.x, tid = threadIdx.x;
    for (int i = tid; i < 30 * PADW; i += 256) {
        int r = i / PADW - 1, c = i % PADW - 1;
        float v = 0.f;
        if (r >= 0 && r < HWD && c >= 0 && c < HWD) v = x[n * IMG + r * HWD + c];
        xs[i] = v;
    }
    __syncthreads();
    if (tid >= 196) return;
    int r = tid / 7, c0 = (tid % 7) * 4;
    float win[18];
#pragma unroll
    for (int ry = 0; ry < 3; ry++)
#pragma unroll
        for (int cx = 0; cx < 6; cx++)
            win[ry * 6 + cx] = xs[(r + ry) * PADW + c0 + cx];
    unsigned int bits0 = 0, bits1 = 0, bits2 = 0, bits3 = 0;
#pragma unroll
    for (int ch = 0; ch < C1; ch++) {
        float k0 = w1b[ch * 9 + 0], k1 = w1b[ch * 9 + 1], k2 = w1b[ch * 9 + 2];
        float k3 = w1b[ch * 9 + 3], k4 = w1b[ch * 9 + 4], k5 = w1b[ch * 9 + 5];
        float k6 = w1b[ch * 9 + 6], k7 = w1b[ch * 9 + 7], k8 = w1b[ch * 9 + 8];
        float b = cb1[ch], m = mean1[ch], sc = scale1[ch], bt = beta1[ch];
#pragma unroll
        for (int px = 0; px < 4; px++) {
            float s = win[px] * k0 + win[px + 1] * k1 + win[px + 2] * k2
                    + win[6 + px] * k3 + win[7 + px] * k4 + win[8 + px] * k5
                    + win[12 + px] * k6 + win[13 + px] * k7 + win[14 + px] * k8;
            float v = fmaxf(s + b, 0.f);
            float val = sc * (v - m) + bt;
            unsigned int bit = (val >= 0.f ? 1u : 0u) << ch;
            if (px == 0) bits0 |= bit;
            else if (px == 1) bits1 |= bit;
            else if (px == 2) bits2 |= bit;
            else bits3 |= bit;
        }
    }
    uint4 w4v = make_uint4(bits0, bits1, bits2, bits3);
    *reinterpret_cast<uint4*>(&s1p[n * IMG + r * HWD + c0]) = w4v;  // 16B aligned
}

// ---------------- conv2 weight packing ----------------
__global__ void pack_w2(const float* __restrict__ w2, unsigned int* __restrict__ w2p) {
    int t = blockIdx.x * blockDim.x + threadIdx.x;
    if (t >= C2 * 9) return;
    int oc = t / 9, k = t % 9;
    unsigned int bits = 0;
    for (int ic = 0; ic < C1; ic++)
        bits |= (w2[oc * 288 + ic * 9 + k] >= 0.f ? 1u : 0u) << ic;
    w2p[t] = bits;
}

// ---------------- fused conv2 + maxpool3s2, register-window (R4, works) ----------------
__global__ __launch_bounds__(256) void conv2pool(const unsigned int* __restrict__ s1p,
                                                 const unsigned int* __restrict__ w2p,
                                                 short* __restrict__ p2i) {
    __shared__ unsigned int spad[29 * PADW];   // rows -1..27, cols -1..28 (3.5 KB)
    __shared__ short scr[OCCHUNK * SCRS];      // 11.8 KB
    int n = blockIdx.x, tid = threadIdx.x;
    for (int i = tid; i < 29 * PADW; i += 256) {
        int r = i / PADW, c = i - r * PADW;
        unsigned int v = 0;
        if (r >= 1 && c >= 1 && c <= 28) v = s1p[n * IMG + (r - 1) * HWD + (c - 1)];
        spad[i] = v;
    }
    __syncthreads();
    unsigned int win[3][9];
    bool top_[3], left_[3];
    bool act2 = (tid + 512) < CONV * CONV;
#pragma unroll
    for (int pi = 0; pi < 3; pi++) {
        int p = tid + pi * 256;
        if (p >= CONV * CONV) p = 0;
        int y = p / CONV, xx = p - y * CONV;
        top_[pi] = (y == 0);
        left_[pi] = (xx == 0);
        const unsigned int* bp = &spad[y * PADW + xx];
#pragma unroll
        for (int ky = 0; ky < 3; ky++)
#pragma unroll
            for (int kx = 0; kx < 3; kx++)
                win[pi][ky * 3 + kx] = bp[ky * PADW + kx];
    }
    for (int base = 0; base < C2; base += OCCHUNK) {
        for (int ol = 0; ol < OCCHUNK; ol++) {
            int oc = base + ol;
            unsigned int w0 = w2p[oc * 9 + 0], w1 = w2p[oc * 9 + 1], w2 = w2p[oc * 9 + 2];
            unsigned int w3 = w2p[oc * 9 + 3], w4 = w2p[oc * 9 + 4], w5 = w2p[oc * 9 + 5];
            unsigned int w6 = w2p[oc * 9 + 6], w7 = w2p[oc * 9 + 7], w8 = w2p[oc * 9 + 8];
            int p0 = __popc(w0), p1 = __popc(w1), p2 = __popc(w2);
            int p3 = __popc(w3), p6 = __popc(w6);
            int ct = 192 + 2 * (p0 + p1 + p2);
            int cl = 192 + 2 * (p0 + p3 + p6);
            int cc = 128 + 2 * (p0 + p1 + p2 + p3 + p6);
#pragma unroll
            for (int pi = 0; pi < 3; pi++) {
                int s = __popc(win[pi][0] ^ w0) + __popc(win[pi][1] ^ w1) + __popc(win[pi][2] ^ w2)
                      + __popc(win[pi][3] ^ w3) + __popc(win[pi][4] ^ w4) + __popc(win[pi][5] ^ w5)
                      + __popc(win[pi][6] ^ w6) + __popc(win[pi][7] ^ w7) + __popc(win[pi][8] ^ w8);
                int off = top_[pi] ? (left_[pi] ? cc : ct) : (left_[pi] ? cl : 288);
                if (pi < 2 || act2) scr[ol * SCRS + tid + pi * 256] = (short)(off - 2 * s);
            }
        }
        __syncthreads();
        for (int q = tid; q < OCCHUNK * PP; q += 256) {
            int ol = q / PP, pix = q - ol * PP;
            int py = pix / PD, px = pix - py * PD;
            const short* rr = &scr[ol * SCRS + (2 * py) * CONV + 2 * px];
            int m0 = max(max((int)rr[0], (int)rr[1]), (int)rr[2]);
            int m1 = max(max((int)rr[CONV], (int)rr[CONV + 1]), (int)rr[CONV + 2]);
            int m2 = max(max((int)rr[2 * CONV], (int)rr[2 * CONV + 1]), (int)rr[2 * CONV + 2]);
            p2i[n * F3 + (base + ol) * PP + pix] = (short)max(max(m0, m1), m2);
        }
        __syncthreads();
    }
}

// ---------------- stats over pooled layer-2 ----------------
// 2048 blocks (one sample), coalesced lane->p, wave owns 16 chs, shuffle-reduce,
// per-block float partials (no atomics).
__global__ __launch_bounds__(256) void p2_stats(const short* __restrict__ p2i,
                         const float* __restrict__ cb2,
                         const float* __restrict__ meanIn, float* __restrict__ part, int pass) {
    int n = blockIdx.x, tid = threadIdx.x, lane = tid & 63, wv = tid >> 6;
    const short* rowb = p2i + (size_t)n * F3;
    __shared__ float red[C2];
#pragma unroll
    for (int i = 0; i < 16; i++) {
        int ch = wv * 16 + i;
        const short* row = rowb + ch * PP;
        float b = cb2[ch];
        float m = pass ? meanIn[ch] : 0.f;
        float a = 0.f;
        for (int p = lane; p < PP; p += 64) {
            float v = fmaxf((float)row[p] + b, 0.f);
            if (pass == 0) a += v;
            else { float c = v - m; a += fabsf(c) * ap2mag(c); }
        }
        for (int off = 32; off; off >>= 1) a += __shfl_down(a, off);
        if (lane == 0) red[ch] = a;
    }
    __syncthreads();
    if (tid < C2) part[n * C2 + tid] = red[tid];
}

// ---------------- stage-2: reduce per-block partials, emit mean or scale ----------------
__global__ __launch_bounds__(256) void reduce_stats(const float* __restrict__ part, int nch, int nblk,
                             const float* __restrict__ g, float* __restrict__ outv,
                             int mode, double count) {
    int ch = blockIdx.x, tid = threadIdx.x;
    double a = 0.0;
    for (int i = tid; i < nblk; i += 256) a += (double)part[(size_t)i * nch + ch];
    __shared__ double red[4];
    for (int off = 32; off; off >>= 1) a += __shfl_down(a, off);
    int lane = tid & 63, wv = tid >> 6;
    if (lane == 0) red[wv] = a;
    __syncthreads();
    if (tid == 0) {
        double s = red[0] + red[1] + red[2] + red[3];
        if (mode == 0) {
            outv[ch] = (float)(s / count);
        } else {
            float var = (float)(s / count);
            float t = var + 1e-4f;
            float inv = 1.0f / sqrtf(t);
            double p = exp2(rint(log2((double)inv)));
            float gg = g[ch];
            float ap2g;
            if (gg == 0.f) ap2g = 0.f;
            else {
                double ag = fabs((double)gg);
                if (ag < 1e-38) ag = 1e-38;
                ap2g = (float)exp2(rint(log2(ag)));
                if (gg < 0.f) ap2g = -ap2g;
            }
            outv[ch] = ap2g * (float)p;
        }
    }
}

// binarize layer-2 -> packed u64 rows; grid-stride over wave-words.
__global__ void p2_pack(const short* __restrict__ p2i, const float* __restrict__ cb2,
                        const float* __restrict__ mean2, const float* __restrict__ scale2,
                        const float* __restrict__ beta2, unsigned long long* __restrict__ hp3) {
    int lane = threadIdx.x & 63;
    int wid = (blockIdx.x * blockDim.x + threadIdx.x) >> 6;
    int nw = (gridDim.x * blockDim.x) >> 6;
    for (int w = wid; w < BB * K3W; w += nw) {
        int n = w / K3W, j = w - n * K3W;
        int f = j * 64 + lane;
        int oc = f / PP;
        float v = fmaxf((float)p2i[n * F3 + f] + cb2[oc], 0.f);
        float val = scale2[oc] * (v - mean2[oc]) + beta2[oc];
        unsigned long long mask = __ballot(val >= 0.f);
        if (lane == 0) hp3[w] = mask;
    }
}

__global__ void w3_pack(const float* __restrict__ w3, unsigned long long* __restrict__ wp3) {
    int lane = threadIdx.x & 63;
    int wid = (blockIdx.x * blockDim.x + threadIdx.x) >> 6;
    int nw = (gridDim.x * blockDim.x) >> 6;
    for (int w = wid; w < N3 * K3W; w += nw) {
        int nn = w / K3W, j = w - nn * K3W;
        float wv = w3[(size_t)nn * F3 + j * 64 + lane];
        unsigned long long mask = __ballot(wv >= 0.f);
        if (lane == 0) wp3[w] = mask;
    }
}

// ---------------- lin3: XNOR-popcount GEMM, 64x64 tile, 4x4 per thread ----------------
__global__ __launch_bounds__(256) void lin3_gemm(const unsigned long long* __restrict__ hp3,
                                                 const unsigned long long* __restrict__ wp3,
                                                 const float* __restrict__ b3l,
                                                 float* __restrict__ h3) {
    __shared__ unsigned long long aT[64][9];
    __shared__ unsigned long long bT[64][9];
    int tx = threadIdx.x & 15, ty = threadIdx.x >> 4;
    int m0 = blockIdx.y * 64, n0 = blockIdx.x * 64;
    int s[4][4];
#pragma unroll
    for (int i = 0; i < 4; i++)
#pragma unroll
        for (int j = 0; j < 4; j++) s[i][j] = 0;
    for (int k0 = 0; k0 < K3W; k0 += 8) {
        for (int t = threadIdx.x; t < 512; t += 256) {
            int r = t >> 3, kk = t & 7;
            int k = k0 + kk;
            aT[r][kk] = (k < K3W) ? hp3[(m0 + r) * K3W + k] : 0ULL;
            bT[r][kk] = (k < K3W) ? wp3[(n0 + r) * K3W + k] : 0ULL;
        }
        __syncthreads();
#pragma unroll
        for (int kk = 0; kk < 8; kk++) {
            unsigned long long a[4], b[4];
#pragma unroll
            for (int i = 0; i < 4; i++) a[i] = aT[ty * 4 + i][kk];
#pragma unroll
            for (int j = 0; j < 4; j++) b[j] = bT[tx * 4 + j][kk];
#pragma unroll
            for (int i = 0; i < 4; i++)
#pragma unroll
                for (int j = 0; j < 4; j++) s[i][j] += __popcll(a[i] ^ b[j]);
        }
        __syncthreads();
    }
#pragma unroll
    for (int i = 0; i < 4; i++) {
        int m = m0 + ty * 4 + i;
#pragma unroll
        for (int j = 0; j < 4; j++) {
            int nn = n0 + tx * 4 + j;
            float v = fmaxf((float)(F3 - 2 * s[i][j]) + b3l[nn], 0.f);
            h3[(size_t)m * N3 + nn] = v;
        }
    }
}

// ---------------- stats over h3 (per feature, across batch) ----------------
__global__ void h3_stats(const float* __restrict__ h3, const float* __restrict__ meanIn,
                         double* __restrict__ outSum, int pass) {
    int nn = blockIdx.x * 256 + threadIdx.x;
    int m0 = blockIdx.y * 128;
    float m = pass ? meanIn[nn] : 0.f;
    float acc = 0.f;
    for (int mm = m0; mm < m0 + 128; mm++) {
        float v = h3[(size_t)mm * N3 + nn];
        if (pass == 0) acc += v;
        else { float c = v - m; acc += fabsf(c) * ap2mag(c); }
    }
    atomicAdd(&outSum[nn], (double)acc);
}

__global__ void h3_pack(const float* __restrict__ h3, const float* __restrict__ mean3,
                        const float* __restrict__ scale3, const float* __restrict__ beta3,
                        unsigned long long* __restrict__ h4p) {
    int lane = threadIdx.x & 63;
    int wid = (blockIdx.x * blockDim.x + threadIdx.x) >> 6;
    int nw = (gridDim.x * blockDim.x) >> 6;
    for (int w = wid; w < BB * K4W; w += nw) {
        int m = w / K4W, j = w - m * K4W;
        int f = j * 64 + lane;
        float v = h3[(size_t)m * N3 + f];
        float val = scale3[f] * (v - mean3[f]) + beta3[f];
        unsigned long long mask = __ballot(val >= 0.f);
        if (lane == 0) h4p[w] = mask;
    }
}

__global__ void w4_pack(const float* __restrict__ w4, unsigned long long* __restrict__ wp4) {
    int gw = (blockIdx.x * blockDim.x + threadIdx.x) >> 6;
    int lane = threadIdx.x & 63;
    if (gw >= NOUT * K4W) return;
    int o = gw / K4W, j = gw % K4W;
    float w = w4[o * N3 + j * 64 + lane];
    unsigned long long mask = __ballot(w >= 0.f);
    if (lane == 0) wp4[o * K4W + j] = mask;
}

// one thread per (m,o); weights in LDS with stride 33 (pad breaks 10-way conflict)
__global__ __launch_bounds__(256) void lin4_out(const unsigned long long* __restrict__ h4p,
                                                const unsigned long long* __restrict__ wp4,
                                                const float* __restrict__ b4,
                                                float* __restrict__ out) {
    __shared__ unsigned long long w[NOUT * 33];
    int tid = threadIdx.x;
    for (int i = tid; i < NOUT * K4W; i += 256) w[(i / K4W) * 33 + (i % K4W)] = wp4[i];
    __syncthreads();
    int g = blockIdx.x * 256 + tid;  // 80 blocks * 256 = 20480 exactly
    int m = g / NOUT, o = g - m * NOUT;
    const unsigned long long* h = &h4p[(size_t)m * K4W];
    int c = 0;
#pragma unroll
    for (int k = 0; k < K4W; k++) c += __popcll(h[k] ^ w[o * 33 + k]);
    out[g] = (float)(N3 - 2 * c) + b4[o];
}

// ---------------- small finalize kernels (h3 path) ----------------
__global__ void finalize_mean(const double* __restrict__ sumd, float* __restrict__ meanOut,
                              int n, double count) {
    int i = blockIdx.x * blockDim.x + threadIdx.x;
    if (i < n) meanOut[i] = (float)(sumd[i] / count);
}

__global__ void finalize_scale(const double* __restrict__ vard, const float* __restrict__ g,
                               float* __restrict__ scaleOut, int n, double count) {
    int i = blockIdx.x * blockDim.x + threadIdx.x;
    if (i >= n) return;
    float var = (float)(vard[i] / count);
    float t = var + 1e-4f;
    float inv = 1.0f / sqrtf(t);
    double p = exp2(rint(log2((double)inv)));
    float gg = g[i];
    float ap2g;
    if (gg == 0.f) ap2g = 0.f;
    else {
        double ag = fabs((double)gg);
        if (ag < 1e-38) ag = 1e-38;
        ap2g = (float)exp2(rint(log2(ag)));
        if (gg < 0.f) ap2g = -ap2g;
    }
    scaleOut[i] = ap2g * (float)p;
}

extern "C" void kernel_launch(void* const* d_in, const int* in_sizes, int n_in,
                              void* d_out, int out_size, void* d_ws, size_t ws_size,
                              hipStream_t stream) {
    const float* x   = (const float*)d_in[0];
    const float* w1  = (const float*)d_in[1];
    const float* cb1 = (const float*)d_in[2];
    const float* g1  = (const float*)d_in[3];
    const float* bt1 = (const float*)d_in[4];
    const float* w2  = (const float*)d_in[5];
    const float* cb2 = (const float*)d_in[6];
    const float* g2  = (const float*)d_in[7];
    const float* bt2 = (const float*)d_in[8];
    const float* w3  = (const float*)d_in[9];
    const float* b3l = (const float*)d_in[10];
    const float* g3  = (const float*)d_in[11];
    const float* bt3 = (const float*)d_in[12];
    const float* w4  = (const float*)d_in[13];
    const float* b4l = (const float*)d_in[14];
    float* out = (float*)d_out;

    char* base = (char*)d_ws;
    size_t off = 0;
    auto carve = [&](size_t bytes) { char* p = base + off; off = (off + bytes + 255) & ~(size_t)255; return p; };
    unsigned int* s1p       = (unsigned int*)carve((size_t)BB * IMG * 4);
    short* p2i              = (short*)carve((size_t)BB * C2 * PP * 2);
    unsigned long long* hp3 = (unsigned long long*)carve((size_t)BB * K3W * 8);
    unsigned long long* wp3 = (unsigned long long*)carve((size_t)N3 * K3W * 8);
    float* h3               = (float*)carve((size_t)BB * N3 * 4);
    unsigned long long* h4p = (unsigned long long*)carve((size_t)BB * K4W * 8);
    unsigned long long* wp4 = (unsigned long long*)carve((size_t)NOUT * K4W * 8);
    unsigned int* w2p       = (unsigned int*)carve((size_t)C2 * 9 * 4);
    float* w1b              = (float*)carve((size_t)C1 * 9 * 4);
    float* part1            = (float*)carve((size_t)BB * C1 * 4);
    float* part2            = (float*)carve((size_t)BB * C2 * 4);
    double* sums            = (double*)carve((size_t)(2048 + 2048) * 8);
    double* sum3d = sums;        // 2048
    double* var3d = sums + 2048; // 2048
    float* fstats           = (float*)carve((size_t)(32 + 32 + 64 + 64 + 2048 + 2048) * 4);
    float* mean1 = fstats;          float* scale1 = fstats + 32;
    float* mean2 = fstats + 64;     float* scale2 = fstats + 128;
    float* mean3 = fstats + 192;    float* scale3 = fstats + 2240;

    hipMemsetAsync(sums, 0, (size_t)(2048 + 2048) * 8, stream);

    // layer 1
    pack_w1<<<1, 288, 0, stream>>>(w1, w1b);
    conv1_stats<<<BB, 256, 0, stream>>>(x, w1b, cb1, mean1, part1, 0);
    reduce_stats<<<C1, 256, 0, stream>>>(part1, C1, BB, g1, mean1, 0, (double)BB * IMG);
    conv1_stats<<<BB, 256, 0, stream>>>(x, w1b, cb1, mean1, part1, 1);
    reduce_stats<<<C1, 256, 0, stream>>>(part1, C1, BB, g1, scale1, 1, (double)BB * IMG);
    conv1_pack<<<BB, 256, 0, stream>>>(x, w1b, cb1, mean1, scale1, bt1, s1p);

    // layer 2
    pack_w2<<<1, 576, 0, stream>>>(w2, w2p);
    conv2pool<<<BB, 256, 0, stream>>>(s1p, w2p, p2i);
    p2_stats<<<BB, 256, 0, stream>>>(p2i, cb2, mean2, part2, 0);
    reduce_stats<<<C2, 256, 0, stream>>>(part2, C2, BB, g2, mean2, 0, (double)BB * PP);
    p2_stats<<<BB, 256, 0, stream>>>(p2i, cb2, mean2, part2, 1);
    reduce_stats<<<C2, 256, 0, stream>>>(part2, C2, BB, g2, scale2, 1, (double)BB * PP);
    p2_pack<<<1024, 256, 0, stream>>>(p2i, cb2, mean2, scale2, bt2, hp3);

    // lin3
    w3_pack<<<2048, 256, 0, stream>>>(w3, wp3);
    lin3_gemm<<<dim3(32, 32), 256, 0, stream>>>(hp3, wp3, b3l, h3);
    h3_stats<<<dim3(8, 16), 256, 0, stream>>>(h3, mean3, sum3d, 0);
    finalize_mean<<<8, 256, 0, stream>>>(sum3d, mean3, 2048, (double)BB);
    h3_stats<<<dim3(8, 16), 256, 0, stream>>>(h3, mean3, var3d, 1);
    finalize_scale<<<8, 256, 0, stream>>>(var3d, g3, scale3, 2048, (double)BB);
    h3_pack<<<256, 256, 0, stream>>>(h3, mean3, scale3, bt3, h4p);

    // lin4
    w4_pack<<<(NOUT * K4W + 3) / 4, 256, 0, stream>>>(w4, wp4);
    lin4_out<<<80, 256, 0, stream>>>(h4p, wp4, b4l, out);

    (void)in_sizes; (void)n_in; (void)out_size; (void)ws_size;
}

// Round 6
// 706.967 us; speedup vs baseline: 2.0300x; 1.0243x over previous
//
#include <hip/hip_runtime.h>

#define BB 2048
#define IMG 784
#define HWD 28
#define C1 32
#define C2 64
#define PP 169
#define PD 13
#define F3 10816
#define N3 2048
#define K3W 169
#define K4W 32
#define NOUT 10
#define CONV 27          // pooled-used conv2 output region is 27x27
#define PADW 30          // padded image row stride (cols -1..28)
#define OCCHUNK 8        // ocs per conv2pool scratch phase
#define SCRS 736         // 729 padded

typedef unsigned long long u64;

__device__ __forceinline__ float ap2mag(float c) {
    // 2^round(log2(max(|c|,1e-38)))  (round half to even, like jnp.round)
    float a = fmaxf(fabsf(c), 1e-38f);
    return exp2f(rintf(log2f(a)));
}

// ---------------- all weight binarization/packing in ONE dispatch ----------------
// blocks 0..2047 grid-stride the big w3 pack; blocks 0/1/2 additionally do w1/w2/w4.
__global__ __launch_bounds__(256) void pack_weights(const float* __restrict__ w1, float* __restrict__ w1b,
                                                    const float* __restrict__ w2, unsigned int* __restrict__ w2p,
                                                    const float* __restrict__ w3, u64* __restrict__ wp3,
                                                    const float* __restrict__ w4, u64* __restrict__ wp4) {
    int tid = threadIdx.x, bid = blockIdx.x;
    int lane = tid & 63;
    int wid = (bid * 256 + tid) >> 6;
    int nw = (gridDim.x * 256) >> 6;
    for (int w = wid; w < N3 * K3W; w += nw) {
        int nn = w / K3W, j = w - nn * K3W;
        float wv = w3[(size_t)nn * F3 + j * 64 + lane];
        u64 mask = __ballot(wv >= 0.f);
        if (lane == 0) wp3[w] = mask;
    }
    if (bid == 0) {
        for (int i = tid; i < C1 * 9; i += 256) w1b[i] = (w1[i] >= 0.f) ? 1.f : -1.f;
    } else if (bid == 1) {
        for (int t = tid; t < C2 * 9; t += 256) {
            int oc = t / 9, k = t % 9;
            unsigned int bits = 0;
            for (int ic = 0; ic < C1; ic++)
                bits |= (w2[oc * 288 + ic * 9 + k] >= 0.f ? 1u : 0u) << ic;
            w2p[t] = bits;
        }
    } else if (bid == 2) {
        for (int w = tid >> 6; w < NOUT * K4W; w += 4) {
            int o = w / K4W, j = w % K4W;
            float wv = w4[o * N3 + j * 64 + lane];
            u64 mask = __ballot(wv >= 0.f);
            if (lane == 0) wp4[w] = mask;
        }
    }
}

// ---------------- conv1 (fp32 x, binarized weights), register-window ----------------
__global__ __launch_bounds__(256) void conv1_stats(const float* __restrict__ x,
                            const float* __restrict__ w1b,
                            const float* __restrict__ cb1, const float* __restrict__ meanIn,
                            float* __restrict__ part, int pass) {
    __shared__ float xs[30 * PADW];
    __shared__ float red[4 * C1];
    int n = blockIdx.x, tid = threadIdx.x;
    for (int i = tid; i < 30 * PADW; i += 256) {
        int r = i / PADW - 1, c = i % PADW - 1;
        float v = 0.f;
        if (r >= 0 && r < HWD && c >= 0 && c < HWD) v = x[n * IMG + r * HWD + c];
        xs[i] = v;
    }
    __syncthreads();
    bool act = tid < 196;
    int r = tid / 7, c0 = (tid % 7) * 4;
    float win[18];
#pragma unroll
    for (int k = 0; k < 18; k++) win[k] = 0.f;
    if (act) {
#pragma unroll
        for (int ry = 0; ry < 3; ry++)
#pragma unroll
            for (int cx = 0; cx < 6; cx++)
                win[ry * 6 + cx] = xs[(r + ry) * PADW + c0 + cx];
    }
    float acc[C1];
#pragma unroll
    for (int ch = 0; ch < C1; ch++) acc[ch] = 0.f;
    if (act) {
#pragma unroll
        for (int ch = 0; ch < C1; ch++) {
            float k0 = w1b[ch * 9 + 0], k1 = w1b[ch * 9 + 1], k2 = w1b[ch * 9 + 2];
            float k3 = w1b[ch * 9 + 3], k4 = w1b[ch * 9 + 4], k5 = w1b[ch * 9 + 5];
            float k6 = w1b[ch * 9 + 6], k7 = w1b[ch * 9 + 7], k8 = w1b[ch * 9 + 8];
            float b = cb1[ch];
            float m = pass ? meanIn[ch] : 0.f;
            float a = 0.f;
#pragma unroll
            for (int px = 0; px < 4; px++) {
                float s = win[px] * k0 + win[px + 1] * k1 + win[px + 2] * k2
                        + win[6 + px] * k3 + win[7 + px] * k4 + win[8 + px] * k5
                        + win[12 + px] * k6 + win[13 + px] * k7 + win[14 + px] * k8;
                float v = fmaxf(s + b, 0.f);
                if (pass == 0) a += v;
                else { float c = v - m; a += fabsf(c) * ap2mag(c); }
            }
            acc[ch] = a;
        }
    }
    int lane = tid & 63, wv = tid >> 6;
#pragma unroll
    for (int ch = 0; ch < C1; ch++) {
        float a = acc[ch];
        for (int off = 32; off; off >>= 1) a += __shfl_down(a, off);
        if (lane == 0) red[wv * C1 + ch] = a;
    }
    __syncthreads();
    if (tid < C1) part[n * C1 + tid] = red[tid] + red[C1 + tid] + red[2 * C1 + tid] + red[3 * C1 + tid];
}

// binarize(shift_bn(relu(conv1))) -> 32 channel bits per pixel, aligned uint4 store.
__global__ __launch_bounds__(256) void conv1_pack(const float* __restrict__ x,
                           const float* __restrict__ w1b,
                           const float* __restrict__ cb1, const float* __restrict__ mean1,
                           const float* __restrict__ scale1, const float* __restrict__ beta1,
                           unsigned int* __restrict__ s1p) {
    __shared__ float xs[30 * PADW];
    int n = blockIdx.x, tid = threadIdx.x;
    for (int i = tid; i < 30 * PADW; i += 256) {
        int r = i / PADW - 1, c = i % PADW - 1;
        float v = 0.f;
        if (r >= 0 && r < HWD && c >= 0 && c < HWD) v = x[n * IMG + r * HWD + c];
        xs[i] = v;
    }
    __syncthreads();
    if (tid >= 196) return;
    int r = tid / 7, c0 = (tid % 7) * 4;
    float win[18];
#pragma unroll
    for (int ry = 0; ry < 3; ry++)
#pragma unroll
        for (int cx = 0; cx < 6; cx++)
            win[ry * 6 + cx] = xs[(r + ry) * PADW + c0 + cx];
    unsigned int bits0 = 0, bits1 = 0, bits2 = 0, bits3 = 0;
#pragma unroll
    for (int ch = 0; ch < C1; ch++) {
        float k0 = w1b[ch * 9 + 0], k1 = w1b[ch * 9 + 1], k2 = w1b[ch * 9 + 2];
        float k3 = w1b[ch * 9 + 3], k4 = w1b[ch * 9 + 4], k5 = w1b[ch * 9 + 5];
        float k6 = w1b[ch * 9 + 6], k7 = w1b[ch * 9 + 7], k8 = w1b[ch * 9 + 8];
        float b = cb1[ch], m = mean1[ch], sc = scale1[ch], bt = beta1[ch];
#pragma unroll
        for (int px = 0; px < 4; px++) {
            float s = win[px] * k0 + win[px + 1] * k1 + win[px + 2] * k2
                    + win[6 + px] * k3 + win[7 + px] * k4 + win[8 + px] * k5
                    + win[12 + px] * k6 + win[13 + px] * k7 + win[14 + px] * k8;
            float v = fmaxf(s + b, 0.f);
            float val = sc * (v - m) + bt;
            unsigned int bit = (val >= 0.f ? 1u : 0u) << ch;
            if (px == 0) bits0 |= bit;
            else if (px == 1) bits1 |= bit;
            else if (px == 2) bits2 |= bit;
            else bits3 |= bit;
        }
    }
    uint4 w4v = make_uint4(bits0, bits1, bits2, bits3);
    *reinterpret_cast<uint4*>(&s1p[n * IMG + r * HWD + c0]) = w4v;  // 16B aligned
}

// ---------------- fused conv2 + maxpool3s2 + per-sample mean partials ----------------
__global__ __launch_bounds__(256) void conv2pool(const unsigned int* __restrict__ s1p,
                                                 const unsigned int* __restrict__ w2p,
                                                 const float* __restrict__ cb2,
                                                 short* __restrict__ p2i,
                                                 float* __restrict__ part2) {
    __shared__ unsigned int spad[29 * PADW];   // 3.5 KB
    __shared__ short scr[OCCHUNK * SCRS];      // 11.8 KB
    __shared__ float psum[OCCHUNK * PP];       // 5.4 KB
    __shared__ float pm[C2];
    int n = blockIdx.x, tid = threadIdx.x;
    for (int i = tid; i < 29 * PADW; i += 256) {
        int r = i / PADW, c = i - r * PADW;
        unsigned int v = 0;
        if (r >= 1 && c >= 1 && c <= 28) v = s1p[n * IMG + (r - 1) * HWD + (c - 1)];
        spad[i] = v;
    }
    __syncthreads();
    unsigned int win[3][9];
    bool top_[3], left_[3];
    bool act2 = (tid + 512) < CONV * CONV;
#pragma unroll
    for (int pi = 0; pi < 3; pi++) {
        int p = tid + pi * 256;
        if (p >= CONV * CONV) p = 0;
        int y = p / CONV, xx = p - y * CONV;
        top_[pi] = (y == 0);
        left_[pi] = (xx == 0);
        const unsigned int* bp = &spad[y * PADW + xx];
#pragma unroll
        for (int ky = 0; ky < 3; ky++)
#pragma unroll
            for (int kx = 0; kx < 3; kx++)
                win[pi][ky * 3 + kx] = bp[ky * PADW + kx];
    }
    int lane = tid & 63, wv = tid >> 6;
    for (int base = 0; base < C2; base += OCCHUNK) {
        for (int ol = 0; ol < OCCHUNK; ol++) {
            int oc = base + ol;
            unsigned int w0 = w2p[oc * 9 + 0], w1 = w2p[oc * 9 + 1], w2 = w2p[oc * 9 + 2];
            unsigned int w3 = w2p[oc * 9 + 3], w4 = w2p[oc * 9 + 4], w5 = w2p[oc * 9 + 5];
            unsigned int w6 = w2p[oc * 9 + 6], w7 = w2p[oc * 9 + 7], w8 = w2p[oc * 9 + 8];
            int p0 = __popc(w0), p1 = __popc(w1), p2 = __popc(w2);
            int p3 = __popc(w3), p6 = __popc(w6);
            int ct = 192 + 2 * (p0 + p1 + p2);
            int cl = 192 + 2 * (p0 + p3 + p6);
            int cc = 128 + 2 * (p0 + p1 + p2 + p3 + p6);
#pragma unroll
            for (int pi = 0; pi < 3; pi++) {
                int s = __popc(win[pi][0] ^ w0) + __popc(win[pi][1] ^ w1) + __popc(win[pi][2] ^ w2)
                      + __popc(win[pi][3] ^ w3) + __popc(win[pi][4] ^ w4) + __popc(win[pi][5] ^ w5)
                      + __popc(win[pi][6] ^ w6) + __popc(win[pi][7] ^ w7) + __popc(win[pi][8] ^ w8);
                int off = top_[pi] ? (left_[pi] ? cc : ct) : (left_[pi] ? cl : 288);
                if (pi < 2 || act2) scr[ol * SCRS + tid + pi * 256] = (short)(off - 2 * s);
            }
        }
        __syncthreads();
        for (int q = tid; q < OCCHUNK * PP; q += 256) {
            int ol = q / PP, pix = q - ol * PP;
            int py = pix / PD, px = pix - py * PD;
            const short* rr = &scr[ol * SCRS + (2 * py) * CONV + 2 * px];
            int m0 = max(max((int)rr[0], (int)rr[1]), (int)rr[2]);
            int m1 = max(max((int)rr[CONV], (int)rr[CONV + 1]), (int)rr[CONV + 2]);
            int m2 = max(max((int)rr[2 * CONV], (int)rr[2 * CONV + 1]), (int)rr[2 * CONV + 2]);
            int val = max(max(m0, m1), m2);
            p2i[n * F3 + (base + ol) * PP + pix] = (short)val;
            psum[q] = fmaxf((float)val + cb2[base + ol], 0.f);
        }
        __syncthreads();
        for (int ol = wv; ol < OCCHUNK; ol += 4) {
            float a = 0.f;
            for (int p = lane; p < PP; p += 64) a += psum[ol * PP + p];
            for (int off = 32; off; off >>= 1) a += __shfl_down(a, off);
            if (lane == 0) pm[base + ol] = a;
        }
        __syncthreads();
    }
    if (tid < C2) part2[n * C2 + tid] = pm[tid];
}

// ---------------- var pass over pooled layer-2 (mean fused into conv2pool) ----------------
__global__ __launch_bounds__(256) void p2_var(const short* __restrict__ p2i,
                         const float* __restrict__ cb2,
                         const float* __restrict__ mean2, float* __restrict__ part) {
    int n = blockIdx.x, tid = threadIdx.x, lane = tid & 63, wv = tid >> 6;
    const short* rowb = p2i + (size_t)n * F3;
    __shared__ float red[C2];
#pragma unroll
    for (int i = 0; i < 16; i++) {
        int ch = wv * 16 + i;
        const short* row = rowb + ch * PP;
        float b = cb2[ch];
        float m = mean2[ch];
        float a = 0.f;
        for (int p = lane; p < PP; p += 64) {
            float v = fmaxf((float)row[p] + b, 0.f);
            float c = v - m;
            a += fabsf(c) * ap2mag(c);
        }
        for (int off = 32; off; off >>= 1) a += __shfl_down(a, off);
        if (lane == 0) red[ch] = a;
    }
    __syncthreads();
    if (tid < C2) part[n * C2 + tid] = red[tid];
}

// ---------------- stage-2: reduce per-block float partials, emit mean or scale ----------------
__global__ __launch_bounds__(256) void reduce_stats(const float* __restrict__ part, int nch, int nblk,
                             const float* __restrict__ g, float* __restrict__ outv,
                             int mode, double count) {
    int ch = blockIdx.x, tid = threadIdx.x;
    double a = 0.0;
    for (int i = tid; i < nblk; i += 256) a += (double)part[(size_t)i * nch + ch];
    __shared__ double red[4];
    for (int off = 32; off; off >>= 1) a += __shfl_down(a, off);
    int lane = tid & 63, wv = tid >> 6;
    if (lane == 0) red[wv] = a;
    __syncthreads();
    if (tid == 0) {
        double s = red[0] + red[1] + red[2] + red[3];
        if (mode == 0) {
            outv[ch] = (float)(s / count);
        } else {
            float var = (float)(s / count);
            float t = var + 1e-4f;
            float inv = 1.0f / sqrtf(t);
            double p = exp2(rint(log2((double)inv)));
            float gg = g[ch];
            float ap2g;
            if (gg == 0.f) ap2g = 0.f;
            else {
                double ag = fabs((double)gg);
                if (ag < 1e-38) ag = 1e-38;
                ap2g = (float)exp2(rint(log2(ag)));
                if (gg < 0.f) ap2g = -ap2g;
            }
            outv[ch] = ap2g * (float)p;
        }
    }
}

// same, double partials
__global__ __launch_bounds__(256) void reduce_statsd(const double* __restrict__ part, int nch, int nblk,
                             const float* __restrict__ g, float* __restrict__ outv,
                             int mode, double count) {
    int ch = blockIdx.x, tid = threadIdx.x;
    double a = 0.0;
    for (int i = tid; i < nblk; i += 256) a += part[(size_t)i * nch + ch];
    __shared__ double red[4];
    for (int off = 32; off; off >>= 1) a += __shfl_down(a, off);
    int lane = tid & 63, wv = tid >> 6;
    if (lane == 0) red[wv] = a;
    __syncthreads();
    if (tid == 0) {
        double s = red[0] + red[1] + red[2] + red[3];
        if (mode == 0) {
            outv[ch] = (float)(s / count);
        } else {
            float var = (float)(s / count);
            float t = var + 1e-4f;
            float inv = 1.0f / sqrtf(t);
            double p = exp2(rint(log2((double)inv)));
            float gg = g[ch];
            float ap2g;
            if (gg == 0.f) ap2g = 0.f;
            else {
                double ag = fabs((double)gg);
                if (ag < 1e-38) ag = 1e-38;
                ap2g = (float)exp2(rint(log2(ag)));
                if (gg < 0.f) ap2g = -ap2g;
            }
            outv[ch] = ap2g * (float)p;
        }
    }
}

// binarize layer-2 -> packed u64 rows; grid-stride over wave-words.
__global__ void p2_pack(const short* __restrict__ p2i, const float* __restrict__ cb2,
                        const float* __restrict__ mean2, const float* __restrict__ scale2,
                        const float* __restrict__ beta2, u64* __restrict__ hp3) {
    int lane = threadIdx.x & 63;
    int wid = (blockIdx.x * blockDim.x + threadIdx.x) >> 6;
    int nw = (gridDim.x * blockDim.x) >> 6;
    for (int w = wid; w < BB * K3W; w += nw) {
        int n = w / K3W, j = w - n * K3W;
        int f = j * 64 + lane;
        int oc = f / PP;
        float v = fmaxf((float)p2i[n * F3 + f] + cb2[oc], 0.f);
        float val = scale2[oc] * (v - mean2[oc]) + beta2[oc];
        u64 mask = __ballot(val >= 0.f);
        if (lane == 0) hp3[w] = mask;
    }
}

// ---------------- lin3: XNOR-popcount GEMM, 64x64 tile, 4x4 per thread ----------------
// R5 fix: thread owns columns j*16+tx (not tx*4+j); B stored as bT[kk][64] so the
// 16 tx lanes read 16 consecutive u64 = all 32 banks -> conflict-free (was 4-way).
// Epilogue: per-block column sums -> part3 (h3 mean partials, fuses h3_stats pass0).
__global__ __launch_bounds__(256) void lin3_gemm(const u64* __restrict__ hp3,
                                                 const u64* __restrict__ wp3,
                                                 const float* __restrict__ b3l,
                                                 float* __restrict__ h3,
                                                 float* __restrict__ part3) {
    __shared__ u64 aT[64][9];
    __shared__ u64 bT[8][64];
    __shared__ float csr[16][64];
    int tid = threadIdx.x;
    int tx = tid & 15, ty = tid >> 4;
    int m0 = blockIdx.y * 64, n0 = blockIdx.x * 64;
    int s[4][4];
#pragma unroll
    for (int i = 0; i < 4; i++)
#pragma unroll
        for (int j = 0; j < 4; j++) s[i][j] = 0;
    for (int k0 = 0; k0 < K3W; k0 += 8) {
        for (int t = tid; t < 512; t += 256) {
            int r = t >> 3, kk = t & 7;
            int k = k0 + kk;
            aT[r][kk] = (k < K3W) ? hp3[(m0 + r) * K3W + k] : 0ULL;
            bT[kk][r] = (k < K3W) ? wp3[(n0 + r) * K3W + k] : 0ULL;
        }
        __syncthreads();
#pragma unroll
        for (int kk = 0; kk < 8; kk++) {
            u64 a[4], b[4];
#pragma unroll
            for (int i = 0; i < 4; i++) a[i] = aT[ty * 4 + i][kk];
#pragma unroll
            for (int j = 0; j < 4; j++) b[j] = bT[kk][j * 16 + tx];
#pragma unroll
            for (int i = 0; i < 4; i++)
#pragma unroll
                for (int j = 0; j < 4; j++) s[i][j] += __popcll(a[i] ^ b[j]);
        }
        __syncthreads();
    }
    float cs[4] = {0.f, 0.f, 0.f, 0.f};
#pragma unroll
    for (int i = 0; i < 4; i++) {
        int m = m0 + ty * 4 + i;
#pragma unroll
        for (int j = 0; j < 4; j++) {
            int nn = n0 + j * 16 + tx;
            float v = fmaxf((float)(F3 - 2 * s[i][j]) + b3l[nn], 0.f);
            h3[(size_t)m * N3 + nn] = v;
            cs[j] += v;
        }
    }
#pragma unroll
    for (int j = 0; j < 4; j++) csr[ty][j * 16 + tx] = cs[j];
    __syncthreads();
    if (tid < 64) {
        float t = 0.f;
        for (int r = 0; r < 16; r++) t += csr[r][tid];
        part3[(size_t)blockIdx.y * N3 + n0 + tid] = t;
    }
}

// ---------------- h3 var partials (mean fused into lin3_gemm) ----------------
__global__ void h3_var(const float* __restrict__ h3, const float* __restrict__ mean3,
                       double* __restrict__ part) {
    int nn = blockIdx.x * 256 + threadIdx.x;
    int m0 = blockIdx.y * 128;
    float m = mean3[nn];
    double acc = 0.0;
    for (int mm = m0; mm < m0 + 128; mm++) {
        float v = h3[(size_t)mm * N3 + nn];
        float c = v - m;
        acc += (double)(fabsf(c) * ap2mag(c));
    }
    part[(size_t)blockIdx.y * N3 + nn] = acc;
}

__global__ void h3_pack(const float* __restrict__ h3, const float* __restrict__ mean3,
                        const float* __restrict__ scale3, const float* __restrict__ beta3,
                        u64* __restrict__ h4p) {
    int lane = threadIdx.x & 63;
    int wid = (blockIdx.x * blockDim.x + threadIdx.x) >> 6;
    int nw = (gridDim.x * blockDim.x) >> 6;
    for (int w = wid; w < BB * K4W; w += nw) {
        int m = w / K4W, j = w - m * K4W;
        int f = j * 64 + lane;
        float v = h3[(size_t)m * N3 + f];
        float val = scale3[f] * (v - mean3[f]) + beta3[f];
        u64 mask = __ballot(val >= 0.f);
        if (lane == 0) h4p[w] = mask;
    }
}

// one thread per (m,o); weights in LDS with stride 33 (pad breaks 10-way conflict)
__global__ __launch_bounds__(256) void lin4_out(const u64* __restrict__ h4p,
                                                const u64* __restrict__ wp4,
                                                const float* __restrict__ b4,
                                                float* __restrict__ out) {
    __shared__ u64 w[NOUT * 33];
    int tid = threadIdx.x;
    for (int i = tid; i < NOUT * K4W; i += 256) w[(i / K4W) * 33 + (i % K4W)] = wp4[i];
    __syncthreads();
    int g = blockIdx.x * 256 + tid;  // 80 blocks * 256 = 20480 exactly
    int m = g / NOUT, o = g - m * NOUT;
    const u64* h = &h4p[(size_t)m * K4W];
    int c = 0;
#pragma unroll
    for (int k = 0; k < K4W; k++) c += __popcll(h[k] ^ w[o * 33 + k]);
    out[g] = (float)(N3 - 2 * c) + b4[o];
}

extern "C" void kernel_launch(void* const* d_in, const int* in_sizes, int n_in,
                              void* d_out, int out_size, void* d_ws, size_t ws_size,
                              hipStream_t stream) {
    const float* x   = (const float*)d_in[0];
    const float* w1  = (const float*)d_in[1];
    const float* cb1 = (const float*)d_in[2];
    const float* g1  = (const float*)d_in[3];
    const float* bt1 = (const float*)d_in[4];
    const float* w2  = (const float*)d_in[5];
    const float* cb2 = (const float*)d_in[6];
    const float* g2  = (const float*)d_in[7];
    const float* bt2 = (const float*)d_in[8];
    const float* w3  = (const float*)d_in[9];
    const float* b3l = (const float*)d_in[10];
    const float* g3  = (const float*)d_in[11];
    const float* bt3 = (const float*)d_in[12];
    const float* w4  = (const float*)d_in[13];
    const float* b4l = (const float*)d_in[14];
    float* out = (float*)d_out;

    char* base = (char*)d_ws;
    size_t off = 0;
    auto carve = [&](size_t bytes) { char* p = base + off; off = (off + bytes + 255) & ~(size_t)255; return p; };
    unsigned int* s1p  = (unsigned int*)carve((size_t)BB * IMG * 4);
    short* p2i         = (short*)carve((size_t)BB * C2 * PP * 2);
    u64* hp3           = (u64*)carve((size_t)BB * K3W * 8);
    u64* wp3           = (u64*)carve((size_t)N3 * K3W * 8);
    float* h3          = (float*)carve((size_t)BB * N3 * 4);
    u64* h4p           = (u64*)carve((size_t)BB * K4W * 8);
    u64* wp4           = (u64*)carve((size_t)NOUT * K4W * 8);
    unsigned int* w2p  = (unsigned int*)carve((size_t)C2 * 9 * 4);
    float* w1b         = (float*)carve((size_t)C1 * 9 * 4);
    float* part1       = (float*)carve((size_t)BB * C1 * 4);
    float* part2       = (float*)carve((size_t)BB * C2 * 4);
    float* part3       = (float*)carve((size_t)32 * N3 * 4);
    double* part3d     = (double*)carve((size_t)16 * N3 * 8);
    float* fstats      = (float*)carve((size_t)(32 + 32 + 64 + 64 + 2048 + 2048) * 4);
    float* mean1 = fstats;          float* scale1 = fstats + 32;
    float* mean2 = fstats + 64;     float* scale2 = fstats + 128;
    float* mean3 = fstats + 192;    float* scale3 = fstats + 2240;

    // weights (w1/w2/w3/w4) in one dispatch
    pack_weights<<<2048, 256, 0, stream>>>(w1, w1b, w2, w2p, w3, wp3, w4, wp4);

    // layer 1
    conv1_stats<<<BB, 256, 0, stream>>>(x, w1b, cb1, mean1, part1, 0);
    reduce_stats<<<C1, 256, 0, stream>>>(part1, C1, BB, g1, mean1, 0, (double)BB * IMG);
    conv1_stats<<<BB, 256, 0, stream>>>(x, w1b, cb1, mean1, part1, 1);
    reduce_stats<<<C1, 256, 0, stream>>>(part1, C1, BB, g1, scale1, 1, (double)BB * IMG);
    conv1_pack<<<BB, 256, 0, stream>>>(x, w1b, cb1, mean1, scale1, bt1, s1p);

    // layer 2 (mean partials fused into conv2pool)
    conv2pool<<<BB, 256, 0, stream>>>(s1p, w2p, cb2, p2i, part2);
    reduce_stats<<<C2, 256, 0, stream>>>(part2, C2, BB, g2, mean2, 0, (double)BB * PP);
    p2_var<<<BB, 256, 0, stream>>>(p2i, cb2, mean2, part2);
    reduce_stats<<<C2, 256, 0, stream>>>(part2, C2, BB, g2, scale2, 1, (double)BB * PP);
    p2_pack<<<1024, 256, 0, stream>>>(p2i, cb2, mean2, scale2, bt2, hp3);

    // lin3 (h3 mean partials fused into gemm epilogue)
    lin3_gemm<<<dim3(32, 32), 256, 0, stream>>>(hp3, wp3, b3l, h3, part3);
    reduce_stats<<<N3, 256, 0, stream>>>(part3, N3, 32, g3, mean3, 0, (double)BB);
    h3_var<<<dim3(8, 16), 256, 0, stream>>>(h3, mean3, part3d);
    reduce_statsd<<<N3, 256, 0, stream>>>(part3d, N3, 16, g3, scale3, 1, (double)BB);
    h3_pack<<<256, 256, 0, stream>>>(h3, mean3, scale3, bt3, h4p);

    // lin4
    lin4_out<<<80, 256, 0, stream>>>(h4p, wp4, b4l, out);

    (void)in_sizes; (void)n_in; (void)out_size; (void)ws_size;
}

// Round 7
// 665.416 us; speedup vs baseline: 2.1567x; 1.0624x over previous
//
#include <hip/hip_runtime.h>

#define BB 2048
#define IMG 784
#define HWD 28
#define C1 32
#define C2 64
#define PP 169
#define PD 13
#define F3 10816
#define N3 2048
#define K3W 169
#define K3P 176          // K words padded to multiple of 8 (pads zero-filled)
#define K4W 32
#define NOUT 10
#define CONV 27          // pooled-used conv2 output region is 27x27
#define PADW 30          // padded row stride (cols -1..28)
#define OCCHUNK 8
#define SCRS 736         // 729 padded

typedef unsigned long long u64;

// ap2 magnitude, EXACT: 2^round(log2|c|). round crosses at mantissa sqrt(2);
// ties impossible (sqrt2 irrational). c==0 -> 0 (always multiplied by |c|=0).
__device__ __forceinline__ float ap2mag(float c) {
    unsigned int a = __float_as_uint(c) & 0x7fffffffu;
    unsigned int e = (a >> 23) + ((a & 0x7fffffu) > 0x3504f3u);
    return __uint_as_float(e << 23);
}
// signed ap2 for gamma (0 -> 0)
__device__ __forceinline__ float ap2sgn(float g) {
    unsigned int u = __float_as_uint(g);
    unsigned int a = u & 0x7fffffffu;
    if (a == 0) return 0.f;
    unsigned int e = (a >> 23) + ((a & 0x7fffffu) > 0x3504f3u);
    return __uint_as_float((u & 0x80000000u) | (e << 23));
}

// ---------------- stage0: conv1 mean partials + ALL weight packing ----------------
__global__ __launch_bounds__(256) void stage0(const float* __restrict__ x,
                                              const float* __restrict__ w1, const float* __restrict__ cb1,
                                              float* __restrict__ part1, float* __restrict__ w1b,
                                              const float* __restrict__ w2, unsigned int* __restrict__ w2p,
                                              const float* __restrict__ w3, u64* __restrict__ wp3,
                                              const float* __restrict__ w4, u64* __restrict__ wp4) {
    __shared__ float xs[30 * PADW];
    __shared__ float red[4 * C1];
    int n = blockIdx.x, tid = threadIdx.x;
    int lane = tid & 63, wv = tid >> 6;
    // w3 pack chunk (grid-stride, padded stride K3P, pad words = 0)
    {
        int wid = (n * 256 + tid) >> 6;
        int nw = (gridDim.x * 256) >> 6;
        for (int w = wid; w < N3 * K3P; w += nw) {
            int nn = w / K3P, j = w - nn * K3P;
            u64 mask = 0;
            if (j < K3W) {
                float wvl = w3[(size_t)nn * F3 + j * 64 + lane];
                mask = __ballot(wvl >= 0.f);
            }
            if (lane == 0) wp3[w] = mask;
        }
    }
    if (n == 0) {
        for (int i = tid; i < C1 * 9; i += 256) w1b[i] = (w1[i] >= 0.f) ? 1.f : -1.f;
    } else if (n == 1) {
        for (int t = tid; t < C2 * 9; t += 256) {
            int oc = t / 9, k = t % 9;
            unsigned int bits = 0;
            for (int ic = 0; ic < C1; ic++)
                bits |= (w2[oc * 288 + ic * 9 + k] >= 0.f ? 1u : 0u) << ic;
            w2p[t] = bits;
        }
    } else if (n == 2) {
        for (int w = wv; w < NOUT * K4W; w += 4) {
            int o = w / K4W, j = w % K4W;
            float wvl = w4[o * N3 + j * 64 + lane];
            u64 mask = __ballot(wvl >= 0.f);
            if (lane == 0) wp4[w] = mask;
        }
    }
    // conv1 pass0 (mean partials); binarize w1 inline via scalar loads
    for (int i = tid; i < 30 * PADW; i += 256) {
        int r = i / PADW - 1, c = i % PADW - 1;
        float v = 0.f;
        if (r >= 0 && r < HWD && c >= 0 && c < HWD) v = x[n * IMG + r * HWD + c];
        xs[i] = v;
    }
    __syncthreads();
    bool act = tid < 196;
    int r = tid / 7, c0 = (tid % 7) * 4;
    float win[18];
#pragma unroll
    for (int k = 0; k < 18; k++) win[k] = 0.f;
    if (act) {
#pragma unroll
        for (int ry = 0; ry < 3; ry++)
#pragma unroll
            for (int cx = 0; cx < 6; cx++)
                win[ry * 6 + cx] = xs[(r + ry) * PADW + c0 + cx];
    }
#pragma unroll
    for (int ch = 0; ch < C1; ch++) {
        float a = 0.f;
        if (act) {
            float k0 = (w1[ch * 9 + 0] >= 0.f) ? 1.f : -1.f, k1 = (w1[ch * 9 + 1] >= 0.f) ? 1.f : -1.f;
            float k2 = (w1[ch * 9 + 2] >= 0.f) ? 1.f : -1.f, k3 = (w1[ch * 9 + 3] >= 0.f) ? 1.f : -1.f;
            float k4 = (w1[ch * 9 + 4] >= 0.f) ? 1.f : -1.f, k5 = (w1[ch * 9 + 5] >= 0.f) ? 1.f : -1.f;
            float k6 = (w1[ch * 9 + 6] >= 0.f) ? 1.f : -1.f, k7 = (w1[ch * 9 + 7] >= 0.f) ? 1.f : -1.f;
            float k8 = (w1[ch * 9 + 8] >= 0.f) ? 1.f : -1.f;
            float b = cb1[ch];
#pragma unroll
            for (int px = 0; px < 4; px++) {
                float s = win[px] * k0 + win[px + 1] * k1 + win[px + 2] * k2
                        + win[6 + px] * k3 + win[7 + px] * k4 + win[8 + px] * k5
                        + win[12 + px] * k6 + win[13 + px] * k7 + win[14 + px] * k8;
                a += fmaxf(s + b, 0.f);
            }
        }
        for (int off = 32; off; off >>= 1) a += __shfl_down(a, off);
        if (lane == 0) red[wv * C1 + ch] = a;
    }
    __syncthreads();
    if (tid < C1) part1[n * C1 + tid] = red[tid] + red[C1 + tid] + red[2 * C1 + tid] + red[3 * C1 + tid];
}

// ---------------- conv1 var partials ----------------
__global__ __launch_bounds__(256) void conv1_var(const float* __restrict__ x,
                            const float* __restrict__ w1b,
                            const float* __restrict__ cb1, const float* __restrict__ mean1,
                            float* __restrict__ part) {
    __shared__ float xs[30 * PADW];
    __shared__ float red[4 * C1];
    int n = blockIdx.x, tid = threadIdx.x;
    for (int i = tid; i < 30 * PADW; i += 256) {
        int r = i / PADW - 1, c = i % PADW - 1;
        float v = 0.f;
        if (r >= 0 && r < HWD && c >= 0 && c < HWD) v = x[n * IMG + r * HWD + c];
        xs[i] = v;
    }
    __syncthreads();
    bool act = tid < 196;
    int r = tid / 7, c0 = (tid % 7) * 4;
    float win[18];
#pragma unroll
    for (int k = 0; k < 18; k++) win[k] = 0.f;
    if (act) {
#pragma unroll
        for (int ry = 0; ry < 3; ry++)
#pragma unroll
            for (int cx = 0; cx < 6; cx++)
                win[ry * 6 + cx] = xs[(r + ry) * PADW + c0 + cx];
    }
    int lane = tid & 63, wv = tid >> 6;
#pragma unroll
    for (int ch = 0; ch < C1; ch++) {
        float a = 0.f;
        if (act) {
            float k0 = w1b[ch * 9 + 0], k1 = w1b[ch * 9 + 1], k2 = w1b[ch * 9 + 2];
            float k3 = w1b[ch * 9 + 3], k4 = w1b[ch * 9 + 4], k5 = w1b[ch * 9 + 5];
            float k6 = w1b[ch * 9 + 6], k7 = w1b[ch * 9 + 7], k8 = w1b[ch * 9 + 8];
            float b = cb1[ch], m = mean1[ch];
#pragma unroll
            for (int px = 0; px < 4; px++) {
                float s = win[px] * k0 + win[px + 1] * k1 + win[px + 2] * k2
                        + win[6 + px] * k3 + win[7 + px] * k4 + win[8 + px] * k5
                        + win[12 + px] * k6 + win[13 + px] * k7 + win[14 + px] * k8;
                float v = fmaxf(s + b, 0.f);
                float c = v - m;
                a += fabsf(c) * ap2mag(c);
            }
        }
        for (int off = 32; off; off >>= 1) a += __shfl_down(a, off);
        if (lane == 0) red[wv * C1 + ch] = a;
    }
    __syncthreads();
    if (tid < C1) part[n * C1 + tid] = red[tid] + red[C1 + tid] + red[2 * C1 + tid] + red[3 * C1 + tid];
}

// ---------------- fused conv1-forward -> binarize(LDS) -> conv2 -> pool ----------------
// s1p never touches HBM: conv1 writes packed bits straight into the padded LDS image.
__global__ __launch_bounds__(256) void conv12(const float* __restrict__ x,
                                              const float* __restrict__ w1b,
                                              const float* __restrict__ cb1, const float* __restrict__ mean1,
                                              const float* __restrict__ scale1, const float* __restrict__ beta1,
                                              const unsigned int* __restrict__ w2p,
                                              const float* __restrict__ cb2,
                                              short* __restrict__ p2i,
                                              float* __restrict__ part2) {
    __shared__ float xs[30 * PADW];            // 3.6 KB
    __shared__ unsigned int spad[29 * PADW];   // 3.5 KB, rows -1..27, cols -1..28
    __shared__ short scr[OCCHUNK * SCRS];      // 11.8 KB
    __shared__ float psum[OCCHUNK * PP];       // 5.4 KB
    __shared__ float pm[C2];
    int n = blockIdx.x, tid = threadIdx.x;
    for (int i = tid; i < 30 * PADW; i += 256) {
        int r = i / PADW - 1, c = i % PADW - 1;
        float v = 0.f;
        if (r >= 0 && r < HWD && c >= 0 && c < HWD) v = x[n * IMG + r * HWD + c];
        xs[i] = v;
    }
    for (int i = tid; i < 29 * PADW; i += 256) spad[i] = 0;
    __syncthreads();
    // conv1 forward + BN + binarize for this thread's 4 pixels
    if (tid < 196) {
        int r = tid / 7, c0 = (tid % 7) * 4;
        float win[18];
#pragma unroll
        for (int ry = 0; ry < 3; ry++)
#pragma unroll
            for (int cx = 0; cx < 6; cx++)
                win[ry * 6 + cx] = xs[(r + ry) * PADW + c0 + cx];
        unsigned int bits0 = 0, bits1 = 0, bits2 = 0, bits3 = 0;
#pragma unroll
        for (int ch = 0; ch < C1; ch++) {
            float k0 = w1b[ch * 9 + 0], k1 = w1b[ch * 9 + 1], k2 = w1b[ch * 9 + 2];
            float k3 = w1b[ch * 9 + 3], k4 = w1b[ch * 9 + 4], k5 = w1b[ch * 9 + 5];
            float k6 = w1b[ch * 9 + 6], k7 = w1b[ch * 9 + 7], k8 = w1b[ch * 9 + 8];
            float b = cb1[ch], m = mean1[ch], sc = scale1[ch], bt = beta1[ch];
#pragma unroll
            for (int px = 0; px < 4; px++) {
                float s = win[px] * k0 + win[px + 1] * k1 + win[px + 2] * k2
                        + win[6 + px] * k3 + win[7 + px] * k4 + win[8 + px] * k5
                        + win[12 + px] * k6 + win[13 + px] * k7 + win[14 + px] * k8;
                float v = fmaxf(s + b, 0.f);
                float val = sc * (v - m) + bt;
                unsigned int bit = (val >= 0.f ? 1u : 0u) << ch;
                if (px == 0) bits0 |= bit;
                else if (px == 1) bits1 |= bit;
                else if (px == 2) bits2 |= bit;
                else bits3 |= bit;
            }
        }
        unsigned int* dst = &spad[(r + 1) * PADW + c0 + 1];
        dst[0] = bits0; dst[1] = bits1; dst[2] = bits2; dst[3] = bits3;
    }
    __syncthreads();
    // conv2 register windows
    unsigned int win2[3][9];
    bool top_[3], left_[3];
    bool act2 = (tid + 512) < CONV * CONV;
#pragma unroll
    for (int pi = 0; pi < 3; pi++) {
        int p = tid + pi * 256;
        if (p >= CONV * CONV) p = 0;
        int y = p / CONV, xx = p - y * CONV;
        top_[pi] = (y == 0);
        left_[pi] = (xx == 0);
        const unsigned int* bp = &spad[y * PADW + xx];
#pragma unroll
        for (int ky = 0; ky < 3; ky++)
#pragma unroll
            for (int kx = 0; kx < 3; kx++)
                win2[pi][ky * 3 + kx] = bp[ky * PADW + kx];
    }
    int lane = tid & 63, wv = tid >> 6;
    for (int base = 0; base < C2; base += OCCHUNK) {
        for (int ol = 0; ol < OCCHUNK; ol++) {
            int oc = base + ol;
            unsigned int w0 = w2p[oc * 9 + 0], w1 = w2p[oc * 9 + 1], w2 = w2p[oc * 9 + 2];
            unsigned int w3 = w2p[oc * 9 + 3], w4 = w2p[oc * 9 + 4], w5 = w2p[oc * 9 + 5];
            unsigned int w6 = w2p[oc * 9 + 6], w7 = w2p[oc * 9 + 7], w8 = w2p[oc * 9 + 8];
            int p0 = __popc(w0), p1 = __popc(w1), p2 = __popc(w2);
            int p3 = __popc(w3), p6 = __popc(w6);
            int ct = 192 + 2 * (p0 + p1 + p2);
            int cl = 192 + 2 * (p0 + p3 + p6);
            int cc = 128 + 2 * (p0 + p1 + p2 + p3 + p6);
#pragma unroll
            for (int pi = 0; pi < 3; pi++) {
                int s = __popc(win2[pi][0] ^ w0) + __popc(win2[pi][1] ^ w1) + __popc(win2[pi][2] ^ w2)
                      + __popc(win2[pi][3] ^ w3) + __popc(win2[pi][4] ^ w4) + __popc(win2[pi][5] ^ w5)
                      + __popc(win2[pi][6] ^ w6) + __popc(win2[pi][7] ^ w7) + __popc(win2[pi][8] ^ w8);
                int off = top_[pi] ? (left_[pi] ? cc : ct) : (left_[pi] ? cl : 288);
                if (pi < 2 || act2) scr[ol * SCRS + tid + pi * 256] = (short)(off - 2 * s);
            }
        }
        __syncthreads();
        for (int q = tid; q < OCCHUNK * PP; q += 256) {
            int ol = q / PP, pix = q - ol * PP;
            int py = pix / PD, px = pix - py * PD;
            const short* rr = &scr[ol * SCRS + (2 * py) * CONV + 2 * px];
            int m0 = max(max((int)rr[0], (int)rr[1]), (int)rr[2]);
            int m1 = max(max((int)rr[CONV], (int)rr[CONV + 1]), (int)rr[CONV + 2]);
            int m2 = max(max((int)rr[2 * CONV], (int)rr[2 * CONV + 1]), (int)rr[2 * CONV + 2]);
            int val = max(max(m0, m1), m2);
            p2i[n * F3 + (base + ol) * PP + pix] = (short)val;
            psum[q] = fmaxf((float)val + cb2[base + ol], 0.f);
        }
        __syncthreads();
        for (int ol = wv; ol < OCCHUNK; ol += 4) {
            float a = 0.f;
            for (int p = lane; p < PP; p += 64) a += psum[ol * PP + p];
            for (int off = 32; off; off >>= 1) a += __shfl_down(a, off);
            if (lane == 0) pm[base + ol] = a;
        }
        __syncthreads();
    }
    if (tid < C2) part2[n * C2 + tid] = pm[tid];
}

// ---------------- p2 var partials ----------------
__global__ __launch_bounds__(256) void p2_var(const short* __restrict__ p2i,
                         const float* __restrict__ cb2,
                         const float* __restrict__ mean2, float* __restrict__ part) {
    int n = blockIdx.x, tid = threadIdx.x, lane = tid & 63, wv = tid >> 6;
    const short* rowb = p2i + (size_t)n * F3;
    __shared__ float red[C2];
#pragma unroll
    for (int i = 0; i < 16; i++) {
        int ch = wv * 16 + i;
        const short* row = rowb + ch * PP;
        float b = cb2[ch];
        float m = mean2[ch];
        float a = 0.f;
        for (int p = lane; p < PP; p += 64) {
            float v = fmaxf((float)row[p] + b, 0.f);
            float c = v - m;
            a += fabsf(c) * ap2mag(c);
        }
        for (int off = 32; off; off >>= 1) a += __shfl_down(a, off);
        if (lane == 0) red[ch] = a;
    }
    __syncthreads();
    if (tid < C2) part[n * C2 + tid] = red[tid];
}

// ---------------- stage-2 reduce: mean or ap2-scale ----------------
__global__ __launch_bounds__(256) void reduce_stats(const float* __restrict__ part, int nch, int nblk,
                             const float* __restrict__ g, float* __restrict__ outv,
                             int mode, double count) {
    int ch = blockIdx.x, tid = threadIdx.x;
    double a = 0.0;
    for (int i = tid; i < nblk; i += 256) a += (double)part[(size_t)i * nch + ch];
    __shared__ double red[4];
    for (int off = 32; off; off >>= 1) a += __shfl_down(a, off);
    int lane = tid & 63, wv = tid >> 6;
    if (lane == 0) red[wv] = a;
    __syncthreads();
    if (tid == 0) {
        double s = red[0] + red[1] + red[2] + red[3];
        if (mode == 0) {
            outv[ch] = (float)(s / count);
        } else {
            float var = (float)(s / count);
            float inv = 1.0f / sqrtf(var + 1e-4f);
            outv[ch] = ap2sgn(g[ch]) * ap2mag(inv);
        }
    }
}

// binarize layer-2 -> packed u64 rows, stride K3P (pads zeroed)
__global__ void p2_pack(const short* __restrict__ p2i, const float* __restrict__ cb2,
                        const float* __restrict__ mean2, const float* __restrict__ scale2,
                        const float* __restrict__ beta2, u64* __restrict__ hp3) {
    int lane = threadIdx.x & 63;
    int wid = (blockIdx.x * blockDim.x + threadIdx.x) >> 6;
    int nw = (gridDim.x * blockDim.x) >> 6;
    for (int w = wid; w < BB * K3P; w += nw) {
        int n = w / K3P, j = w - n * K3P;
        u64 mask = 0;
        if (j < K3W) {
            int f = j * 64 + lane;
            int oc = f / PP;
            float v = fmaxf((float)p2i[n * F3 + f] + cb2[oc], 0.f);
            float val = scale2[oc] * (v - mean2[oc]) + beta2[oc];
            mask = __ballot(val >= 0.f);
        }
        if (lane == 0) hp3[w] = mask;
    }
}

// ---------------- lin3: XNOR-popcount GEMM, 128x64 tile, 8x4 per thread ----------------
// K padded to 176 (no branches). a-reads broadcast, b-reads 128B-contiguous per 16
// lanes: conflict-free. Epilogue: per-block column sums -> part3 (h3 mean partials).
__global__ __launch_bounds__(256) void lin3_gemm(const u64* __restrict__ hp3,
                                                 const u64* __restrict__ wp3,
                                                 const float* __restrict__ b3l,
                                                 float* __restrict__ h3,
                                                 float* __restrict__ part3) {
    __shared__ u64 aT[8][128];   // 8 KB
    __shared__ u64 bT[8][64];    // 4 KB
    __shared__ float csr[4][64];
    int tid = threadIdx.x;
    int tx = tid & 15, ty = tid >> 4;
    int m0 = blockIdx.y * 128, n0 = blockIdx.x * 64;
    int arow = tid >> 1, akk = (tid & 1) * 4;
    int bcol = tid >> 2, bkk = (tid & 3) * 2;
    const u64* aps = &hp3[(size_t)(m0 + arow) * K3P + akk];
    const u64* bps = &wp3[(size_t)(n0 + bcol) * K3P + bkk];
    int s[8][4];
#pragma unroll
    for (int i = 0; i < 8; i++)
#pragma unroll
        for (int j = 0; j < 4; j++) s[i][j] = 0;
    for (int k0 = 0; k0 < K3P; k0 += 8) {
        u64 a0 = aps[0], a1 = aps[1], a2 = aps[2], a3 = aps[3];
        u64 b0 = bps[0], b1 = bps[1];
        aps += 8; bps += 8;
        aT[akk + 0][arow] = a0; aT[akk + 1][arow] = a1;
        aT[akk + 2][arow] = a2; aT[akk + 3][arow] = a3;
        bT[bkk + 0][bcol] = b0; bT[bkk + 1][bcol] = b1;
        __syncthreads();
#pragma unroll
        for (int kk = 0; kk < 8; kk++) {
            u64 b[4], a[8];
#pragma unroll
            for (int j = 0; j < 4; j++) b[j] = bT[kk][j * 16 + tx];
#pragma unroll
            for (int i = 0; i < 8; i++) a[i] = aT[kk][i * 16 + ty];
#pragma unroll
            for (int i = 0; i < 8; i++)
#pragma unroll
                for (int j = 0; j < 4; j++) s[i][j] += (int)__popcll(a[i] ^ b[j]);
        }
        __syncthreads();
    }
    float cs[4] = {0.f, 0.f, 0.f, 0.f};
#pragma unroll
    for (int i = 0; i < 8; i++) {
        int m = m0 + i * 16 + ty;
#pragma unroll
        for (int j = 0; j < 4; j++) {
            int nn = n0 + j * 16 + tx;
            float v = fmaxf((float)(F3 - 2 * s[i][j]) + b3l[nn], 0.f);
            h3[(size_t)m * N3 + nn] = v;
            cs[j] += v;
        }
    }
    int lane = tid & 63, wv = tid >> 6;
#pragma unroll
    for (int j = 0; j < 4; j++) {
        cs[j] += __shfl_xor(cs[j], 16);
        cs[j] += __shfl_xor(cs[j], 32);
        if (lane < 16) csr[wv][j * 16 + lane] = cs[j];
    }
    __syncthreads();
    if (tid < 64)
        part3[(size_t)blockIdx.y * N3 + n0 + tid] =
            csr[0][tid] + csr[1][tid] + csr[2][tid] + csr[3][tid];
}

// ---------------- h3: mean + var + scale, one kernel per column ----------------
__global__ __launch_bounds__(256) void h3_finish(const float* __restrict__ h3,
                                                 const float* __restrict__ part3,
                                                 const float* __restrict__ g3,
                                                 float* __restrict__ mean3, float* __restrict__ scale3) {
    int nn = blockIdx.x, tid = threadIdx.x;
    __shared__ float msh;
    __shared__ double redd[4];
    if (tid < 64) {
        float a = (tid < 16) ? part3[(size_t)tid * N3 + nn] : 0.f;
        for (int off = 8; off; off >>= 1) a += __shfl_down(a, off);
        if (tid == 0) { float m = a / (float)BB; mean3[nn] = m; msh = m; }
    }
    __syncthreads();
    float m = msh;
    float acc = 0.f;
#pragma unroll
    for (int q = 0; q < 8; q++) {
        float v = h3[(size_t)(q * 256 + tid) * N3 + nn];
        float c = v - m;
        acc += fabsf(c) * ap2mag(c);
    }
    double a = (double)acc;
    for (int off = 32; off; off >>= 1) a += __shfl_down(a, off);
    int lane = tid & 63, wv = tid >> 6;
    if (lane == 0) redd[wv] = a;
    __syncthreads();
    if (tid == 0) {
        float var = (float)((redd[0] + redd[1] + redd[2] + redd[3]) / (double)BB);
        float inv = 1.0f / sqrtf(var + 1e-4f);
        scale3[nn] = ap2sgn(g3[nn]) * ap2mag(inv);
    }
}

// ---------------- fused h3 binarize + lin4 (one block per sample) ----------------
__global__ __launch_bounds__(256) void h4_out(const float* __restrict__ h3,
                                              const float* __restrict__ mean3, const float* __restrict__ scale3,
                                              const float* __restrict__ bt3,
                                              const u64* __restrict__ wp4, const float* __restrict__ b4,
                                              float* __restrict__ out) {
    __shared__ u64 hb[K4W];
    __shared__ u64 wsh[NOUT * 33];
    int m = blockIdx.x, tid = threadIdx.x, lane = tid & 63, wv = tid >> 6;
    for (int i = tid; i < NOUT * K4W; i += 256) wsh[(i / K4W) * 33 + (i % K4W)] = wp4[i];
#pragma unroll
    for (int q = 0; q < 8; q++) {
        int j = wv * 8 + q;
        int f = j * 64 + lane;
        float v = h3[(size_t)m * N3 + f];
        float val = scale3[f] * (v - mean3[f]) + bt3[f];
        u64 mask = __ballot(val >= 0.f);
        if (lane == 0) hb[j] = mask;
    }
    __syncthreads();
    if (tid < NOUT) {
        int c = 0;
#pragma unroll
        for (int k = 0; k < K4W; k++) c += (int)__popcll(hb[k] ^ wsh[tid * 33 + k]);
        out[m * NOUT + tid] = (float)(N3 - 2 * c) + b4[tid];
    }
}

extern "C" void kernel_launch(void* const* d_in, const int* in_sizes, int n_in,
                              void* d_out, int out_size, void* d_ws, size_t ws_size,
                              hipStream_t stream) {
    const float* x   = (const float*)d_in[0];
    const float* w1  = (const float*)d_in[1];
    const float* cb1 = (const float*)d_in[2];
    const float* g1  = (const float*)d_in[3];
    const float* bt1 = (const float*)d_in[4];
    const float* w2  = (const float*)d_in[5];
    const float* cb2 = (const float*)d_in[6];
    const float* g2  = (const float*)d_in[7];
    const float* bt2 = (const float*)d_in[8];
    const float* w3  = (const float*)d_in[9];
    const float* b3l = (const float*)d_in[10];
    const float* g3  = (const float*)d_in[11];
    const float* bt3 = (const float*)d_in[12];
    const float* w4  = (const float*)d_in[13];
    const float* b4l = (const float*)d_in[14];
    float* out = (float*)d_out;

    char* base = (char*)d_ws;
    size_t off = 0;
    auto carve = [&](size_t bytes) { char* p = base + off; off = (off + bytes + 255) & ~(size_t)255; return p; };
    short* p2i         = (short*)carve((size_t)BB * C2 * PP * 2);
    u64* hp3           = (u64*)carve((size_t)BB * K3P * 8);
    u64* wp3           = (u64*)carve((size_t)N3 * K3P * 8);
    float* h3          = (float*)carve((size_t)BB * N3 * 4);
    u64* wp4           = (u64*)carve((size_t)NOUT * K4W * 8);
    unsigned int* w2p  = (unsigned int*)carve((size_t)C2 * 9 * 4);
    float* w1b         = (float*)carve((size_t)C1 * 9 * 4);
    float* part1       = (float*)carve((size_t)BB * C1 * 4);
    float* part2       = (float*)carve((size_t)BB * C2 * 4);
    float* part3       = (float*)carve((size_t)16 * N3 * 4);
    float* fstats      = (float*)carve((size_t)(32 + 32 + 64 + 64 + 2048 + 2048) * 4);
    float* mean1 = fstats;          float* scale1 = fstats + 32;
    float* mean2 = fstats + 64;     float* scale2 = fstats + 128;
    float* mean3 = fstats + 192;    float* scale3 = fstats + 2240;

    stage0<<<BB, 256, 0, stream>>>(x, w1, cb1, part1, w1b, w2, w2p, w3, wp3, w4, wp4);
    reduce_stats<<<C1, 256, 0, stream>>>(part1, C1, BB, g1, mean1, 0, (double)BB * IMG);
    conv1_var<<<BB, 256, 0, stream>>>(x, w1b, cb1, mean1, part1);
    reduce_stats<<<C1, 256, 0, stream>>>(part1, C1, BB, g1, scale1, 1, (double)BB * IMG);
    conv12<<<BB, 256, 0, stream>>>(x, w1b, cb1, mean1, scale1, bt1, w2p, cb2, p2i, part2);
    reduce_stats<<<C2, 256, 0, stream>>>(part2, C2, BB, g2, mean2, 0, (double)BB * PP);
    p2_var<<<BB, 256, 0, stream>>>(p2i, cb2, mean2, part2);
    reduce_stats<<<C2, 256, 0, stream>>>(part2, C2, BB, g2, scale2, 1, (double)BB * PP);
    p2_pack<<<1024, 256, 0, stream>>>(p2i, cb2, mean2, scale2, bt2, hp3);
    lin3_gemm<<<dim3(32, 16), 256, 0, stream>>>(hp3, wp3, b3l, h3, part3);
    h3_finish<<<N3, 256, 0, stream>>>(h3, part3, g3, mean3, scale3);
    h4_out<<<BB, 256, 0, stream>>>(h3, mean3, scale3, bt3, wp4, b4l, out);

    (void)in_sizes; (void)n_in; (void)out_size; (void)ws_size;
}

// Round 8
// 624.882 us; speedup vs baseline: 2.2966x; 1.0649x over previous
//
#include <hip/hip_runtime.h>

#define BB 2048
#define IMG 784
#define HWD 28
#define C1 32
#define C2 64
#define PP 169
#define PD 13
#define F3 10816
#define N3 2048
#define K3W 169
#define K3P 176          // K words padded to multiple of 8 (pads zero-filled)
#define K4W 32
#define NOUT 10
#define CONV 27          // pooled-used conv2 output region is 27x27
#define PADW 30          // padded row stride (cols -1..28)
#define OCCHUNK 8
#define OCH 32           // ocs per conv2pool block (2 blocks per sample)
#define SCRS 736         // 729 padded

typedef unsigned long long u64;

// ap2 magnitude, EXACT: 2^round(log2|c|). round crosses at mantissa sqrt(2);
// ties impossible (sqrt2 irrational). c==0 -> 0 (always multiplied by |c|=0).
__device__ __forceinline__ float ap2mag(float c) {
    unsigned int a = __float_as_uint(c) & 0x7fffffffu;
    unsigned int e = (a >> 23) + ((a & 0x7fffffu) > 0x3504f3u);
    return __uint_as_float(e << 23);
}
// signed ap2 for gamma (0 -> 0)
__device__ __forceinline__ float ap2sgn(float g) {
    unsigned int u = __float_as_uint(g);
    unsigned int a = u & 0x7fffffffu;
    if (a == 0) return 0.f;
    unsigned int e = (a >> 23) + ((a & 0x7fffffu) > 0x3504f3u);
    return __uint_as_float((u & 0x80000000u) | (e << 23));
}

// ---------------- stage0: conv1 mean partials + ALL weight packing ----------------
__global__ __launch_bounds__(256) void stage0(const float* __restrict__ x,
                                              const float* __restrict__ w1, const float* __restrict__ cb1,
                                              float* __restrict__ part1, float* __restrict__ w1b,
                                              const float* __restrict__ w2, unsigned int* __restrict__ w2p,
                                              const float* __restrict__ w3, u64* __restrict__ wp3,
                                              const float* __restrict__ w4, u64* __restrict__ wp4) {
    __shared__ float xs[30 * PADW];
    __shared__ float red[4 * C1];
    int n = blockIdx.x, tid = threadIdx.x;
    int lane = tid & 63, wv = tid >> 6;
    // w3 pack chunk (grid-stride, padded stride K3P, pad words = 0)
    {
        int wid = (n * 256 + tid) >> 6;
        int nw = (gridDim.x * 256) >> 6;
        for (int w = wid; w < N3 * K3P; w += nw) {
            int nn = w / K3P, j = w - nn * K3P;
            u64 mask = 0;
            if (j < K3W) {
                float wvl = w3[(size_t)nn * F3 + j * 64 + lane];
                mask = __ballot(wvl >= 0.f);
            }
            if (lane == 0) wp3[w] = mask;
        }
    }
    if (n == 0) {
        for (int i = tid; i < C1 * 9; i += 256) w1b[i] = (w1[i] >= 0.f) ? 1.f : -1.f;
    } else if (n == 1) {
        for (int t = tid; t < C2 * 9; t += 256) {
            int oc = t / 9, k = t % 9;
            unsigned int bits = 0;
            for (int ic = 0; ic < C1; ic++)
                bits |= (w2[oc * 288 + ic * 9 + k] >= 0.f ? 1u : 0u) << ic;
            w2p[t] = bits;
        }
    } else if (n == 2) {
        for (int w = wv; w < NOUT * K4W; w += 4) {
            int o = w / K4W, j = w % K4W;
            float wvl = w4[o * N3 + j * 64 + lane];
            u64 mask = __ballot(wvl >= 0.f);
            if (lane == 0) wp4[w] = mask;
        }
    }
    // conv1 pass0 (mean partials); binarize w1 inline via scalar loads
    for (int i = tid; i < 30 * PADW; i += 256) {
        int r = i / PADW - 1, c = i % PADW - 1;
        float v = 0.f;
        if (r >= 0 && r < HWD && c >= 0 && c < HWD) v = x[n * IMG + r * HWD + c];
        xs[i] = v;
    }
    __syncthreads();
    bool act = tid < 196;
    int r = tid / 7, c0 = (tid % 7) * 4;
    float win[18];
#pragma unroll
    for (int k = 0; k < 18; k++) win[k] = 0.f;
    if (act) {
#pragma unroll
        for (int ry = 0; ry < 3; ry++)
#pragma unroll
            for (int cx = 0; cx < 6; cx++)
                win[ry * 6 + cx] = xs[(r + ry) * PADW + c0 + cx];
    }
#pragma unroll
    for (int ch = 0; ch < C1; ch++) {
        float a = 0.f;
        if (act) {
            float k0 = (w1[ch * 9 + 0] >= 0.f) ? 1.f : -1.f, k1 = (w1[ch * 9 + 1] >= 0.f) ? 1.f : -1.f;
            float k2 = (w1[ch * 9 + 2] >= 0.f) ? 1.f : -1.f, k3 = (w1[ch * 9 + 3] >= 0.f) ? 1.f : -1.f;
            float k4 = (w1[ch * 9 + 4] >= 0.f) ? 1.f : -1.f, k5 = (w1[ch * 9 + 5] >= 0.f) ? 1.f : -1.f;
            float k6 = (w1[ch * 9 + 6] >= 0.f) ? 1.f : -1.f, k7 = (w1[ch * 9 + 7] >= 0.f) ? 1.f : -1.f;
            float k8 = (w1[ch * 9 + 8] >= 0.f) ? 1.f : -1.f;
            float b = cb1[ch];
#pragma unroll
            for (int px = 0; px < 4; px++) {
                float s = win[px] * k0 + win[px + 1] * k1 + win[px + 2] * k2
                        + win[6 + px] * k3 + win[7 + px] * k4 + win[8 + px] * k5
                        + win[12 + px] * k6 + win[13 + px] * k7 + win[14 + px] * k8;
                a += fmaxf(s + b, 0.f);
            }
        }
        for (int off = 32; off; off >>= 1) a += __shfl_down(a, off);
        if (lane == 0) red[wv * C1 + ch] = a;
    }
    __syncthreads();
    if (tid < C1) part1[n * C1 + tid] = red[tid] + red[C1 + tid] + red[2 * C1 + tid] + red[3 * C1 + tid];
}

// ---------------- conv1 var partials ----------------
__global__ __launch_bounds__(256) void conv1_var(const float* __restrict__ x,
                            const float* __restrict__ w1b,
                            const float* __restrict__ cb1, const float* __restrict__ mean1,
                            float* __restrict__ part) {
    __shared__ float xs[30 * PADW];
    __shared__ float red[4 * C1];
    int n = blockIdx.x, tid = threadIdx.x;
    for (int i = tid; i < 30 * PADW; i += 256) {
        int r = i / PADW - 1, c = i % PADW - 1;
        float v = 0.f;
        if (r >= 0 && r < HWD && c >= 0 && c < HWD) v = x[n * IMG + r * HWD + c];
        xs[i] = v;
    }
    __syncthreads();
    bool act = tid < 196;
    int r = tid / 7, c0 = (tid % 7) * 4;
    float win[18];
#pragma unroll
    for (int k = 0; k < 18; k++) win[k] = 0.f;
    if (act) {
#pragma unroll
        for (int ry = 0; ry < 3; ry++)
#pragma unroll
            for (int cx = 0; cx < 6; cx++)
                win[ry * 6 + cx] = xs[(r + ry) * PADW + c0 + cx];
    }
    int lane = tid & 63, wv = tid >> 6;
#pragma unroll
    for (int ch = 0; ch < C1; ch++) {
        float a = 0.f;
        if (act) {
            float k0 = w1b[ch * 9 + 0], k1 = w1b[ch * 9 + 1], k2 = w1b[ch * 9 + 2];
            float k3 = w1b[ch * 9 + 3], k4 = w1b[ch * 9 + 4], k5 = w1b[ch * 9 + 5];
            float k6 = w1b[ch * 9 + 6], k7 = w1b[ch * 9 + 7], k8 = w1b[ch * 9 + 8];
            float b = cb1[ch], m = mean1[ch];
#pragma unroll
            for (int px = 0; px < 4; px++) {
                float s = win[px] * k0 + win[px + 1] * k1 + win[px + 2] * k2
                        + win[6 + px] * k3 + win[7 + px] * k4 + win[8 + px] * k5
                        + win[12 + px] * k6 + win[13 + px] * k7 + win[14 + px] * k8;
                float v = fmaxf(s + b, 0.f);
                float c = v - m;
                a += fabsf(c) * ap2mag(c);
            }
        }
        for (int off = 32; off; off >>= 1) a += __shfl_down(a, off);
        if (lane == 0) red[wv * C1 + ch] = a;
    }
    __syncthreads();
    if (tid < C1) part[n * C1 + tid] = red[tid] + red[C1 + tid] + red[2 * C1 + tid] + red[3 * C1 + tid];
}

// binarize(shift_bn(relu(conv1))) -> 32 channel bits per pixel, aligned uint4 store.
// Kept SEPARATE from conv2pool: R7's fusion pushed VGPR to 124 -> 21% occupancy
// -> 196us. Separate kernels stay under the occupancy cliff.
__global__ __launch_bounds__(256) void conv1_pack(const float* __restrict__ x,
                           const float* __restrict__ w1b,
                           const float* __restrict__ cb1, const float* __restrict__ mean1,
                           const float* __restrict__ scale1, const float* __restrict__ beta1,
                           unsigned int* __restrict__ s1p) {
    __shared__ float xs[30 * PADW];
    int n = blockIdx.x, tid = threadIdx.x;
    for (int i = tid; i < 30 * PADW; i += 256) {
        int r = i / PADW - 1, c = i % PADW - 1;
        float v = 0.f;
        if (r >= 0 && r < HWD && c >= 0 && c < HWD) v = x[n * IMG + r * HWD + c];
        xs[i] = v;
    }
    __syncthreads();
    if (tid >= 196) return;
    int r = tid / 7, c0 = (tid % 7) * 4;
    float win[18];
#pragma unroll
    for (int ry = 0; ry < 3; ry++)
#pragma unroll
        for (int cx = 0; cx < 6; cx++)
            win[ry * 6 + cx] = xs[(r + ry) * PADW + c0 + cx];
    unsigned int bits0 = 0, bits1 = 0, bits2 = 0, bits3 = 0;
#pragma unroll
    for (int ch = 0; ch < C1; ch++) {
        float k0 = w1b[ch * 9 + 0], k1 = w1b[ch * 9 + 1], k2 = w1b[ch * 9 + 2];
        float k3 = w1b[ch * 9 + 3], k4 = w1b[ch * 9 + 4], k5 = w1b[ch * 9 + 5];
        float k6 = w1b[ch * 9 + 6], k7 = w1b[ch * 9 + 7], k8 = w1b[ch * 9 + 8];
        float b = cb1[ch], m = mean1[ch], sc = scale1[ch], bt = beta1[ch];
#pragma unroll
        for (int px = 0; px < 4; px++) {
            float s = win[px] * k0 + win[px + 1] * k1 + win[px + 2] * k2
                    + win[6 + px] * k3 + win[7 + px] * k4 + win[8 + px] * k5
                    + win[12 + px] * k6 + win[13 + px] * k7 + win[14 + px] * k8;
            float v = fmaxf(s + b, 0.f);
            float val = sc * (v - m) + bt;
            unsigned int bit = (val >= 0.f ? 1u : 0u) << ch;
            if (px == 0) bits0 |= bit;
            else if (px == 1) bits1 |= bit;
            else if (px == 2) bits2 |= bit;
            else bits3 |= bit;
        }
    }
    uint4 w4v = make_uint4(bits0, bits1, bits2, bits3);
    *reinterpret_cast<uint4*>(&s1p[n * IMG + r * HWD + c0]) = w4v;  // 16B aligned
}

// ---------------- conv2 + maxpool3s2 + mean partials, 2 blocks/sample ----------------
// blockIdx.y selects 32 ocs: halves per-block serial chain + barrier count,
// doubles resident parallelism vs 1 block/sample.
__global__ __launch_bounds__(256) void conv2pool(const unsigned int* __restrict__ s1p,
                                                 const unsigned int* __restrict__ w2p,
                                                 const float* __restrict__ cb2,
                                                 short* __restrict__ p2i,
                                                 float* __restrict__ part2) {
    __shared__ unsigned int spad[29 * PADW];   // 3.5 KB
    __shared__ short scr[OCCHUNK * SCRS];      // 11.8 KB
    __shared__ float psum[OCCHUNK * PP];       // 5.4 KB
    __shared__ float pm[OCH];
    int n = blockIdx.x, ocb = blockIdx.y * OCH, tid = threadIdx.x;
    for (int i = tid; i < 29 * PADW; i += 256) {
        int r = i / PADW, c = i - r * PADW;
        unsigned int v = 0;
        if (r >= 1 && c >= 1 && c <= 28) v = s1p[n * IMG + (r - 1) * HWD + (c - 1)];
        spad[i] = v;
    }
    __syncthreads();
    unsigned int win[3][9];
    bool top_[3], left_[3];
    bool act2 = (tid + 512) < CONV * CONV;
#pragma unroll
    for (int pi = 0; pi < 3; pi++) {
        int p = tid + pi * 256;
        if (p >= CONV * CONV) p = 0;
        int y = p / CONV, xx = p - y * CONV;
        top_[pi] = (y == 0);
        left_[pi] = (xx == 0);
        const unsigned int* bp = &spad[y * PADW + xx];
#pragma unroll
        for (int ky = 0; ky < 3; ky++)
#pragma unroll
            for (int kx = 0; kx < 3; kx++)
                win[pi][ky * 3 + kx] = bp[ky * PADW + kx];
    }
    int lane = tid & 63, wv = tid >> 6;
    for (int base = 0; base < OCH; base += OCCHUNK) {
        for (int ol = 0; ol < OCCHUNK; ol++) {
            int oc = ocb + base + ol;
            unsigned int w0 = w2p[oc * 9 + 0], w1 = w2p[oc * 9 + 1], w2 = w2p[oc * 9 + 2];
            unsigned int w3 = w2p[oc * 9 + 3], w4 = w2p[oc * 9 + 4], w5 = w2p[oc * 9 + 5];
            unsigned int w6 = w2p[oc * 9 + 6], w7 = w2p[oc * 9 + 7], w8 = w2p[oc * 9 + 8];
            int p0 = __popc(w0), p1 = __popc(w1), p2 = __popc(w2);
            int p3 = __popc(w3), p6 = __popc(w6);
            int ct = 192 + 2 * (p0 + p1 + p2);
            int cl = 192 + 2 * (p0 + p3 + p6);
            int cc = 128 + 2 * (p0 + p1 + p2 + p3 + p6);
#pragma unroll
            for (int pi = 0; pi < 3; pi++) {
                int s = __popc(win[pi][0] ^ w0) + __popc(win[pi][1] ^ w1) + __popc(win[pi][2] ^ w2)
                      + __popc(win[pi][3] ^ w3) + __popc(win[pi][4] ^ w4) + __popc(win[pi][5] ^ w5)
                      + __popc(win[pi][6] ^ w6) + __popc(win[pi][7] ^ w7) + __popc(win[pi][8] ^ w8);
                int off = top_[pi] ? (left_[pi] ? cc : ct) : (left_[pi] ? cl : 288);
                if (pi < 2 || act2) scr[ol * SCRS + tid + pi * 256] = (short)(off - 2 * s);
            }
        }
        __syncthreads();
        for (int q = tid; q < OCCHUNK * PP; q += 256) {
            int ol = q / PP, pix = q - ol * PP;
            int py = pix / PD, px = pix - py * PD;
            const short* rr = &scr[ol * SCRS + (2 * py) * CONV + 2 * px];
            int m0 = max(max((int)rr[0], (int)rr[1]), (int)rr[2]);
            int m1 = max(max((int)rr[CONV], (int)rr[CONV + 1]), (int)rr[CONV + 2]);
            int m2 = max(max((int)rr[2 * CONV], (int)rr[2 * CONV + 1]), (int)rr[2 * CONV + 2]);
            int val = max(max(m0, m1), m2);
            p2i[n * F3 + (ocb + base + ol) * PP + pix] = (short)val;
            psum[q] = fmaxf((float)val + cb2[ocb + base + ol], 0.f);
        }
        __syncthreads();
        for (int ol = wv; ol < OCCHUNK; ol += 4) {
            float a = 0.f;
            for (int p = lane; p < PP; p += 64) a += psum[ol * PP + p];
            for (int off = 32; off; off >>= 1) a += __shfl_down(a, off);
            if (lane == 0) pm[base + ol] = a;
        }
        __syncthreads();
    }
    if (tid < OCH) part2[n * C2 + ocb + tid] = pm[tid];
}

// ---------------- p2 var partials ----------------
__global__ __launch_bounds__(256) void p2_var(const short* __restrict__ p2i,
                         const float* __restrict__ cb2,
                         const float* __restrict__ mean2, float* __restrict__ part) {
    int n = blockIdx.x, tid = threadIdx.x, lane = tid & 63, wv = tid >> 6;
    const short* rowb = p2i + (size_t)n * F3;
    __shared__ float red[C2];
#pragma unroll
    for (int i = 0; i < 16; i++) {
        int ch = wv * 16 + i;
        const short* row = rowb + ch * PP;
        float b = cb2[ch];
        float m = mean2[ch];
        float a = 0.f;
        for (int p = lane; p < PP; p += 64) {
            float v = fmaxf((float)row[p] + b, 0.f);
            float c = v - m;
            a += fabsf(c) * ap2mag(c);
        }
        for (int off = 32; off; off >>= 1) a += __shfl_down(a, off);
        if (lane == 0) red[ch] = a;
    }
    __syncthreads();
    if (tid < C2) part[n * C2 + tid] = red[tid];
}

// ---------------- stage-2 reduce: mean or ap2-scale ----------------
__global__ __launch_bounds__(256) void reduce_stats(const float* __restrict__ part, int nch, int nblk,
                             const float* __restrict__ g, float* __restrict__ outv,
                             int mode, double count) {
    int ch = blockIdx.x, tid = threadIdx.x;
    double a = 0.0;
    for (int i = tid; i < nblk; i += 256) a += (double)part[(size_t)i * nch + ch];
    __shared__ double red[4];
    for (int off = 32; off; off >>= 1) a += __shfl_down(a, off);
    int lane = tid & 63, wv = tid >> 6;
    if (lane == 0) red[wv] = a;
    __syncthreads();
    if (tid == 0) {
        double s = red[0] + red[1] + red[2] + red[3];
        if (mode == 0) {
            outv[ch] = (float)(s / count);
        } else {
            float var = (float)(s / count);
            float inv = 1.0f / sqrtf(var + 1e-4f);
            outv[ch] = ap2sgn(g[ch]) * ap2mag(inv);
        }
    }
}

// binarize layer-2 -> packed u64 rows, stride K3P (pads zeroed)
__global__ void p2_pack(const short* __restrict__ p2i, const float* __restrict__ cb2,
                        const float* __restrict__ mean2, const float* __restrict__ scale2,
                        const float* __restrict__ beta2, u64* __restrict__ hp3) {
    int lane = threadIdx.x & 63;
    int wid = (blockIdx.x * blockDim.x + threadIdx.x) >> 6;
    int nw = (gridDim.x * blockDim.x) >> 6;
    for (int w = wid; w < BB * K3P; w += nw) {
        int n = w / K3P, j = w - n * K3P;
        u64 mask = 0;
        if (j < K3W) {
            int f = j * 64 + lane;
            int oc = f / PP;
            float v = fmaxf((float)p2i[n * F3 + f] + cb2[oc], 0.f);
            float val = scale2[oc] * (v - mean2[oc]) + beta2[oc];
            mask = __ballot(val >= 0.f);
        }
        if (lane == 0) hp3[w] = mask;
    }
}

// ---------------- lin3: XNOR-popcount GEMM, 128x64 tile, 8x4 per thread ----------------
__global__ __launch_bounds__(256) void lin3_gemm(const u64* __restrict__ hp3,
                                                 const u64* __restrict__ wp3,
                                                 const float* __restrict__ b3l,
                                                 float* __restrict__ h3,
                                                 float* __restrict__ part3) {
    __shared__ u64 aT[8][128];   // 8 KB
    __shared__ u64 bT[8][64];    // 4 KB
    __shared__ float csr[4][64];
    int tid = threadIdx.x;
    int tx = tid & 15, ty = tid >> 4;
    int m0 = blockIdx.y * 128, n0 = blockIdx.x * 64;
    int arow = tid >> 1, akk = (tid & 1) * 4;
    int bcol = tid >> 2, bkk = (tid & 3) * 2;
    const u64* aps = &hp3[(size_t)(m0 + arow) * K3P + akk];
    const u64* bps = &wp3[(size_t)(n0 + bcol) * K3P + bkk];
    int s[8][4];
#pragma unroll
    for (int i = 0; i < 8; i++)
#pragma unroll
        for (int j = 0; j < 4; j++) s[i][j] = 0;
    for (int k0 = 0; k0 < K3P; k0 += 8) {
        u64 a0 = aps[0], a1 = aps[1], a2 = aps[2], a3 = aps[3];
        u64 b0 = bps[0], b1 = bps[1];
        aps += 8; bps += 8;
        aT[akk + 0][arow] = a0; aT[akk + 1][arow] = a1;
        aT[akk + 2][arow] = a2; aT[akk + 3][arow] = a3;
        bT[bkk + 0][bcol] = b0; bT[bkk + 1][bcol] = b1;
        __syncthreads();
#pragma unroll
        for (int kk = 0; kk < 8; kk++) {
            u64 b[4], a[8];
#pragma unroll
            for (int j = 0; j < 4; j++) b[j] = bT[kk][j * 16 + tx];
#pragma unroll
            for (int i = 0; i < 8; i++) a[i] = aT[kk][i * 16 + ty];
#pragma unroll
            for (int i = 0; i < 8; i++)
#pragma unroll
                for (int j = 0; j < 4; j++) s[i][j] += (int)__popcll(a[i] ^ b[j]);
        }
        __syncthreads();
    }
    float cs[4] = {0.f, 0.f, 0.f, 0.f};
#pragma unroll
    for (int i = 0; i < 8; i++) {
        int m = m0 + i * 16 + ty;
#pragma unroll
        for (int j = 0; j < 4; j++) {
            int nn = n0 + j * 16 + tx;
            float v = fmaxf((float)(F3 - 2 * s[i][j]) + b3l[nn], 0.f);
            h3[(size_t)m * N3 + nn] = v;
            cs[j] += v;
        }
    }
    int lane = tid & 63, wv = tid >> 6;
#pragma unroll
    for (int j = 0; j < 4; j++) {
        cs[j] += __shfl_xor(cs[j], 16);
        cs[j] += __shfl_xor(cs[j], 32);
        if (lane < 16) csr[wv][j * 16 + lane] = cs[j];
    }
    __syncthreads();
    if (tid < 64)
        part3[(size_t)blockIdx.y * N3 + n0 + tid] =
            csr[0][tid] + csr[1][tid] + csr[2][tid] + csr[3][tid];
}

// ---------------- h3: mean + var + scale, one kernel per column ----------------
__global__ __launch_bounds__(256) void h3_finish(const float* __restrict__ h3,
                                                 const float* __restrict__ part3,
                                                 const float* __restrict__ g3,
                                                 float* __restrict__ mean3, float* __restrict__ scale3) {
    int nn = blockIdx.x, tid = threadIdx.x;
    __shared__ float msh;
    __shared__ double redd[4];
    if (tid < 64) {
        float a = (tid < 16) ? part3[(size_t)tid * N3 + nn] : 0.f;
        for (int off = 8; off; off >>= 1) a += __shfl_down(a, off);
        if (tid == 0) { float m = a / (float)BB; mean3[nn] = m; msh = m; }
    }
    __syncthreads();
    float m = msh;
    float acc = 0.f;
#pragma unroll
    for (int q = 0; q < 8; q++) {
        float v = h3[(size_t)(q * 256 + tid) * N3 + nn];
        float c = v - m;
        acc += fabsf(c) * ap2mag(c);
    }
    double a = (double)acc;
    for (int off = 32; off; off >>= 1) a += __shfl_down(a, off);
    int lane = tid & 63, wv = tid >> 6;
    if (lane == 0) redd[wv] = a;
    __syncthreads();
    if (tid == 0) {
        float var = (float)((redd[0] + redd[1] + redd[2] + redd[3]) / (double)BB);
        float inv = 1.0f / sqrtf(var + 1e-4f);
        scale3[nn] = ap2sgn(g3[nn]) * ap2mag(inv);
    }
}

// ---------------- fused h3 binarize + lin4 (one block per sample) ----------------
__global__ __launch_bounds__(256) void h4_out(const float* __restrict__ h3,
                                              const float* __restrict__ mean3, const float* __restrict__ scale3,
                                              const float* __restrict__ bt3,
                                              const u64* __restrict__ wp4, const float* __restrict__ b4,
                                              float* __restrict__ out) {
    __shared__ u64 hb[K4W];
    __shared__ u64 wsh[NOUT * 33];
    int m = blockIdx.x, tid = threadIdx.x, lane = tid & 63, wv = tid >> 6;
    for (int i = tid; i < NOUT * K4W; i += 256) wsh[(i / K4W) * 33 + (i % K4W)] = wp4[i];
#pragma unroll
    for (int q = 0; q < 8; q++) {
        int j = wv * 8 + q;
        int f = j * 64 + lane;
        float v = h3[(size_t)m * N3 + f];
        float val = scale3[f] * (v - mean3[f]) + bt3[f];
        u64 mask = __ballot(val >= 0.f);
        if (lane == 0) hb[j] = mask;
    }
    __syncthreads();
    if (tid < NOUT) {
        int c = 0;
#pragma unroll
        for (int k = 0; k < K4W; k++) c += (int)__popcll(hb[k] ^ wsh[tid * 33 + k]);
        out[m * NOUT + tid] = (float)(N3 - 2 * c) + b4[tid];
    }
}

extern "C" void kernel_launch(void* const* d_in, const int* in_sizes, int n_in,
                              void* d_out, int out_size, void* d_ws, size_t ws_size,
                              hipStream_t stream) {
    const float* x   = (const float*)d_in[0];
    const float* w1  = (const float*)d_in[1];
    const float* cb1 = (const float*)d_in[2];
    const float* g1  = (const float*)d_in[3];
    const float* bt1 = (const float*)d_in[4];
    const float* w2  = (const float*)d_in[5];
    const float* cb2 = (const float*)d_in[6];
    const float* g2  = (const float*)d_in[7];
    const float* bt2 = (const float*)d_in[8];
    const float* w3  = (const float*)d_in[9];
    const float* b3l = (const float*)d_in[10];
    const float* g3  = (const float*)d_in[11];
    const float* bt3 = (const float*)d_in[12];
    const float* w4  = (const float*)d_in[13];
    const float* b4l = (const float*)d_in[14];
    float* out = (float*)d_out;

    char* base = (char*)d_ws;
    size_t off = 0;
    auto carve = [&](size_t bytes) { char* p = base + off; off = (off + bytes + 255) & ~(size_t)255; return p; };
    unsigned int* s1p  = (unsigned int*)carve((size_t)BB * IMG * 4);
    short* p2i         = (short*)carve((size_t)BB * C2 * PP * 2);
    u64* hp3           = (u64*)carve((size_t)BB * K3P * 8);
    u64* wp3           = (u64*)carve((size_t)N3 * K3P * 8);
    float* h3          = (float*)carve((size_t)BB * N3 * 4);
    u64* wp4           = (u64*)carve((size_t)NOUT * K4W * 8);
    unsigned int* w2p  = (unsigned int*)carve((size_t)C2 * 9 * 4);
    float* w1b         = (float*)carve((size_t)C1 * 9 * 4);
    float* part1       = (float*)carve((size_t)BB * C1 * 4);
    float* part2       = (float*)carve((size_t)BB * C2 * 4);
    float* part3       = (float*)carve((size_t)16 * N3 * 4);
    float* fstats      = (float*)carve((size_t)(32 + 32 + 64 + 64 + 2048 + 2048) * 4);
    float* mean1 = fstats;          float* scale1 = fstats + 32;
    float* mean2 = fstats + 64;     float* scale2 = fstats + 128;
    float* mean3 = fstats + 192;    float* scale3 = fstats + 2240;

    stage0<<<BB, 256, 0, stream>>>(x, w1, cb1, part1, w1b, w2, w2p, w3, wp3, w4, wp4);
    reduce_stats<<<C1, 256, 0, stream>>>(part1, C1, BB, g1, mean1, 0, (double)BB * IMG);
    conv1_var<<<BB, 256, 0, stream>>>(x, w1b, cb1, mean1, part1);
    reduce_stats<<<C1, 256, 0, stream>>>(part1, C1, BB, g1, scale1, 1, (double)BB * IMG);
    conv1_pack<<<BB, 256, 0, stream>>>(x, w1b, cb1, mean1, scale1, bt1, s1p);
    conv2pool<<<dim3(BB, 2), 256, 0, stream>>>(s1p, w2p, cb2, p2i, part2);
    reduce_stats<<<C2, 256, 0, stream>>>(part2, C2, BB, g2, mean2, 0, (double)BB * PP);
    p2_var<<<BB, 256, 0, stream>>>(p2i, cb2, mean2, part2);
    reduce_stats<<<C2, 256, 0, stream>>>(part2, C2, BB, g2, scale2, 1, (double)BB * PP);
    p2_pack<<<1024, 256, 0, stream>>>(p2i, cb2, mean2, scale2, bt2, hp3);
    lin3_gemm<<<dim3(32, 16), 256, 0, stream>>>(hp3, wp3, b3l, h3, part3);
    h3_finish<<<N3, 256, 0, stream>>>(h3, part3, g3, mean3, scale3);
    h4_out<<<BB, 256, 0, stream>>>(h3, mean3, scale3, bt3, wp4, b4l, out);

    (void)in_sizes; (void)n_in; (void)out_size; (void)ws_size;
}

// Round 9
// 593.930 us; speedup vs baseline: 2.4163x; 1.0521x over previous
//
#include <hip/hip_runtime.h>

#define BB 2048
#define IMG 784
#define HWD 28
#define C1 32
#define C2 64
#define PP 169
#define PD 13
#define F3 10816
#define N3 2048
#define K4W 32
#define NOUT 10
#define CONV 27          // pooled-used conv2 output region is 27x27
#define PADW 30          // padded row stride (cols -1..28)
#define OCCHUNK 8
#define OCH 32           // ocs per conv2pool block (2 blocks per sample)
#define SCRS 736         // 729 padded

typedef unsigned long long u64;
typedef int v4i __attribute__((ext_vector_type(4)));

// ap2 magnitude, EXACT: 2^round(log2|c|). round crosses at mantissa sqrt(2).
__device__ __forceinline__ float ap2mag(float c) {
    unsigned int a = __float_as_uint(c) & 0x7fffffffu;
    unsigned int e = (a >> 23) + ((a & 0x7fffffu) > 0x3504f3u);
    return __uint_as_float(e << 23);
}
__device__ __forceinline__ float ap2sgn(float g) {
    unsigned int u = __float_as_uint(g);
    unsigned int a = u & 0x7fffffffu;
    if (a == 0) return 0.f;
    unsigned int e = (a >> 23) + ((a & 0x7fffffu) > 0x3504f3u);
    return __uint_as_float((u & 0x80000000u) | (e << 23));
}

// ---------------- stage0: conv1 mean partials + ALL weight packing ----------------
// w3 now packed to i8 (+1 / -1) planes for the MFMA lin3.
__global__ __launch_bounds__(256) void stage0(const float* __restrict__ x,
                                              const float* __restrict__ w1, const float* __restrict__ cb1,
                                              float* __restrict__ part1, float* __restrict__ w1b,
                                              const float* __restrict__ w2, unsigned int* __restrict__ w2p,
                                              const float* __restrict__ w3, char* __restrict__ wp3i,
                                              const float* __restrict__ w4, u64* __restrict__ wp4) {
    __shared__ float xs[30 * PADW];
    __shared__ float red[4 * C1];
    int n = blockIdx.x, tid = threadIdx.x;
    int lane = tid & 63, wv = tid >> 6;
    // w3 -> i8 (grid-stride over float4 groups)
    {
        int idx = n * 256 + tid;
        int nthr = gridDim.x * 256;
        int total = (N3 * F3) / 4;
        for (int t = idx; t < total; t += nthr) {
            float4 wv4 = *(const float4*)(w3 + (size_t)t * 4);
            unsigned int w = (wv4.x >= 0.f ? 0x01u : 0xffu)
                           | (wv4.y >= 0.f ? 0x01u : 0xffu) << 8
                           | (wv4.z >= 0.f ? 0x01u : 0xffu) << 16
                           | (wv4.w >= 0.f ? 0x01u : 0xffu) << 24;
            *(unsigned int*)(wp3i + (size_t)t * 4) = w;
        }
    }
    if (n == 0) {
        for (int i = tid; i < C1 * 9; i += 256) w1b[i] = (w1[i] >= 0.f) ? 1.f : -1.f;
    } else if (n == 1) {
        for (int t = tid; t < C2 * 9; t += 256) {
            int oc = t / 9, k = t % 9;
            unsigned int bits = 0;
            for (int ic = 0; ic < C1; ic++)
                bits |= (w2[oc * 288 + ic * 9 + k] >= 0.f ? 1u : 0u) << ic;
            w2p[t] = bits;
        }
    } else if (n == 2) {
        for (int w = wv; w < NOUT * K4W; w += 4) {
            int o = w / K4W, j = w % K4W;
            float wvl = w4[o * N3 + j * 64 + lane];
            u64 mask = __ballot(wvl >= 0.f);
            if (lane == 0) wp4[w] = mask;
        }
    }
    // conv1 pass0 (mean partials)
    for (int i = tid; i < 30 * PADW; i += 256) {
        int r = i / PADW - 1, c = i % PADW - 1;
        float v = 0.f;
        if (r >= 0 && r < HWD && c >= 0 && c < HWD) v = x[n * IMG + r * HWD + c];
        xs[i] = v;
    }
    __syncthreads();
    bool act = tid < 196;
    int r = tid / 7, c0 = (tid % 7) * 4;
    float win[18];
#pragma unroll
    for (int k = 0; k < 18; k++) win[k] = 0.f;
    if (act) {
#pragma unroll
        for (int ry = 0; ry < 3; ry++)
#pragma unroll
            for (int cx = 0; cx < 6; cx++)
                win[ry * 6 + cx] = xs[(r + ry) * PADW + c0 + cx];
    }
#pragma unroll
    for (int ch = 0; ch < C1; ch++) {
        float a = 0.f;
        if (act) {
            float k0 = (w1[ch * 9 + 0] >= 0.f) ? 1.f : -1.f, k1 = (w1[ch * 9 + 1] >= 0.f) ? 1.f : -1.f;
            float k2 = (w1[ch * 9 + 2] >= 0.f) ? 1.f : -1.f, k3 = (w1[ch * 9 + 3] >= 0.f) ? 1.f : -1.f;
            float k4 = (w1[ch * 9 + 4] >= 0.f) ? 1.f : -1.f, k5 = (w1[ch * 9 + 5] >= 0.f) ? 1.f : -1.f;
            float k6 = (w1[ch * 9 + 6] >= 0.f) ? 1.f : -1.f, k7 = (w1[ch * 9 + 7] >= 0.f) ? 1.f : -1.f;
            float k8 = (w1[ch * 9 + 8] >= 0.f) ? 1.f : -1.f;
            float b = cb1[ch];
#pragma unroll
            for (int px = 0; px < 4; px++) {
                float s = win[px] * k0 + win[px + 1] * k1 + win[px + 2] * k2
                        + win[6 + px] * k3 + win[7 + px] * k4 + win[8 + px] * k5
                        + win[12 + px] * k6 + win[13 + px] * k7 + win[14 + px] * k8;
                a += fmaxf(s + b, 0.f);
            }
        }
        for (int off = 32; off; off >>= 1) a += __shfl_down(a, off);
        if (lane == 0) red[wv * C1 + ch] = a;
    }
    __syncthreads();
    if (tid < C1) part1[n * C1 + tid] = red[tid] + red[C1 + tid] + red[2 * C1 + tid] + red[3 * C1 + tid];
}

// ---------------- conv1 var partials ----------------
__global__ __launch_bounds__(256) void conv1_var(const float* __restrict__ x,
                            const float* __restrict__ w1b,
                            const float* __restrict__ cb1, const float* __restrict__ mean1,
                            float* __restrict__ part) {
    __shared__ float xs[30 * PADW];
    __shared__ float red[4 * C1];
    int n = blockIdx.x, tid = threadIdx.x;
    for (int i = tid; i < 30 * PADW; i += 256) {
        int r = i / PADW - 1, c = i % PADW - 1;
        float v = 0.f;
        if (r >= 0 && r < HWD && c >= 0 && c < HWD) v = x[n * IMG + r * HWD + c];
        xs[i] = v;
    }
    __syncthreads();
    bool act = tid < 196;
    int r = tid / 7, c0 = (tid % 7) * 4;
    float win[18];
#pragma unroll
    for (int k = 0; k < 18; k++) win[k] = 0.f;
    if (act) {
#pragma unroll
        for (int ry = 0; ry < 3; ry++)
#pragma unroll
            for (int cx = 0; cx < 6; cx++)
                win[ry * 6 + cx] = xs[(r + ry) * PADW + c0 + cx];
    }
    int lane = tid & 63, wv = tid >> 6;
#pragma unroll
    for (int ch = 0; ch < C1; ch++) {
        float a = 0.f;
        if (act) {
            float k0 = w1b[ch * 9 + 0], k1 = w1b[ch * 9 + 1], k2 = w1b[ch * 9 + 2];
            float k3 = w1b[ch * 9 + 3], k4 = w1b[ch * 9 + 4], k5 = w1b[ch * 9 + 5];
            float k6 = w1b[ch * 9 + 6], k7 = w1b[ch * 9 + 7], k8 = w1b[ch * 9 + 8];
            float b = cb1[ch], m = mean1[ch];
#pragma unroll
            for (int px = 0; px < 4; px++) {
                float s = win[px] * k0 + win[px + 1] * k1 + win[px + 2] * k2
                        + win[6 + px] * k3 + win[7 + px] * k4 + win[8 + px] * k5
                        + win[12 + px] * k6 + win[13 + px] * k7 + win[14 + px] * k8;
                float v = fmaxf(s + b, 0.f);
                float c = v - m;
                a += fabsf(c) * ap2mag(c);
            }
        }
        for (int off = 32; off; off >>= 1) a += __shfl_down(a, off);
        if (lane == 0) red[wv * C1 + ch] = a;
    }
    __syncthreads();
    if (tid < C1) part[n * C1 + tid] = red[tid] + red[C1 + tid] + red[2 * C1 + tid] + red[3 * C1 + tid];
}

// binarize(shift_bn(relu(conv1))) -> 32 channel bits per pixel, aligned uint4 store.
__global__ __launch_bounds__(256) void conv1_pack(const float* __restrict__ x,
                           const float* __restrict__ w1b,
                           const float* __restrict__ cb1, const float* __restrict__ mean1,
                           const float* __restrict__ scale1, const float* __restrict__ beta1,
                           unsigned int* __restrict__ s1p) {
    __shared__ float xs[30 * PADW];
    int n = blockIdx.x, tid = threadIdx.x;
    for (int i = tid; i < 30 * PADW; i += 256) {
        int r = i / PADW - 1, c = i % PADW - 1;
        float v = 0.f;
        if (r >= 0 && r < HWD && c >= 0 && c < HWD) v = x[n * IMG + r * HWD + c];
        xs[i] = v;
    }
    __syncthreads();
    if (tid >= 196) return;
    int r = tid / 7, c0 = (tid % 7) * 4;
    float win[18];
#pragma unroll
    for (int ry = 0; ry < 3; ry++)
#pragma unroll
        for (int cx = 0; cx < 6; cx++)
            win[ry * 6 + cx] = xs[(r + ry) * PADW + c0 + cx];
    unsigned int bits0 = 0, bits1 = 0, bits2 = 0, bits3 = 0;
#pragma unroll
    for (int ch = 0; ch < C1; ch++) {
        float k0 = w1b[ch * 9 + 0], k1 = w1b[ch * 9 + 1], k2 = w1b[ch * 9 + 2];
        float k3 = w1b[ch * 9 + 3], k4 = w1b[ch * 9 + 4], k5 = w1b[ch * 9 + 5];
        float k6 = w1b[ch * 9 + 6], k7 = w1b[ch * 9 + 7], k8 = w1b[ch * 9 + 8];
        float b = cb1[ch], m = mean1[ch], sc = scale1[ch], bt = beta1[ch];
#pragma unroll
        for (int px = 0; px < 4; px++) {
            float s = win[px] * k0 + win[px + 1] * k1 + win[px + 2] * k2
                    + win[6 + px] * k3 + win[7 + px] * k4 + win[8 + px] * k5
                    + win[12 + px] * k6 + win[13 + px] * k7 + win[14 + px] * k8;
            float v = fmaxf(s + b, 0.f);
            float val = sc * (v - m) + bt;
            unsigned int bit = (val >= 0.f ? 1u : 0u) << ch;
            if (px == 0) bits0 |= bit;
            else if (px == 1) bits1 |= bit;
            else if (px == 2) bits2 |= bit;
            else bits3 |= bit;
        }
    }
    uint4 w4v = make_uint4(bits0, bits1, bits2, bits3);
    *reinterpret_cast<uint4*>(&s1p[n * IMG + r * HWD + c0]) = w4v;  // 16B aligned
}

// ---------------- conv2 + maxpool3s2 + mean partials, 2 blocks/sample ----------------
__global__ __launch_bounds__(256) void conv2pool(const unsigned int* __restrict__ s1p,
                                                 const unsigned int* __restrict__ w2p,
                                                 const float* __restrict__ cb2,
                                                 short* __restrict__ p2i,
                                                 float* __restrict__ part2) {
    __shared__ unsigned int spad[29 * PADW];   // 3.5 KB
    __shared__ short scr[OCCHUNK * SCRS];      // 11.8 KB
    __shared__ float psum[OCCHUNK * PP];       // 5.4 KB
    __shared__ float pm[OCH];
    int n = blockIdx.x, ocb = blockIdx.y * OCH, tid = threadIdx.x;
    for (int i = tid; i < 29 * PADW; i += 256) {
        int r = i / PADW, c = i - r * PADW;
        unsigned int v = 0;
        if (r >= 1 && c >= 1 && c <= 28) v = s1p[n * IMG + (r - 1) * HWD + (c - 1)];
        spad[i] = v;
    }
    __syncthreads();
    unsigned int win[3][9];
    bool top_[3], left_[3];
    bool act2 = (tid + 512) < CONV * CONV;
#pragma unroll
    for (int pi = 0; pi < 3; pi++) {
        int p = tid + pi * 256;
        if (p >= CONV * CONV) p = 0;
        int y = p / CONV, xx = p - y * CONV;
        top_[pi] = (y == 0);
        left_[pi] = (xx == 0);
        const unsigned int* bp = &spad[y * PADW + xx];
#pragma unroll
        for (int ky = 0; ky < 3; ky++)
#pragma unroll
            for (int kx = 0; kx < 3; kx++)
                win[pi][ky * 3 + kx] = bp[ky * PADW + kx];
    }
    int lane = tid & 63, wv = tid >> 6;
    for (int base = 0; base < OCH; base += OCCHUNK) {
        for (int ol = 0; ol < OCCHUNK; ol++) {
            int oc = ocb + base + ol;
            unsigned int w0 = w2p[oc * 9 + 0], w1 = w2p[oc * 9 + 1], w2 = w2p[oc * 9 + 2];
            unsigned int w3 = w2p[oc * 9 + 3], w4 = w2p[oc * 9 + 4], w5 = w2p[oc * 9 + 5];
            unsigned int w6 = w2p[oc * 9 + 6], w7 = w2p[oc * 9 + 7], w8 = w2p[oc * 9 + 8];
            int p0 = __popc(w0), p1 = __popc(w1), p2 = __popc(w2);
            int p3 = __popc(w3), p6 = __popc(w6);
            int ct = 192 + 2 * (p0 + p1 + p2);
            int cl = 192 + 2 * (p0 + p3 + p6);
            int cc = 128 + 2 * (p0 + p1 + p2 + p3 + p6);
#pragma unroll
            for (int pi = 0; pi < 3; pi++) {
                int s = __popc(win[pi][0] ^ w0) + __popc(win[pi][1] ^ w1) + __popc(win[pi][2] ^ w2)
                      + __popc(win[pi][3] ^ w3) + __popc(win[pi][4] ^ w4) + __popc(win[pi][5] ^ w5)
                      + __popc(win[pi][6] ^ w6) + __popc(win[pi][7] ^ w7) + __popc(win[pi][8] ^ w8);
                int off = top_[pi] ? (left_[pi] ? cc : ct) : (left_[pi] ? cl : 288);
                if (pi < 2 || act2) scr[ol * SCRS + tid + pi * 256] = (short)(off - 2 * s);
            }
        }
        __syncthreads();
        for (int q = tid; q < OCCHUNK * PP; q += 256) {
            int ol = q / PP, pix = q - ol * PP;
            int py = pix / PD, px = pix - py * PD;
            const short* rr = &scr[ol * SCRS + (2 * py) * CONV + 2 * px];
            int m0 = max(max((int)rr[0], (int)rr[1]), (int)rr[2]);
            int m1 = max(max((int)rr[CONV], (int)rr[CONV + 1]), (int)rr[CONV + 2]);
            int m2 = max(max((int)rr[2 * CONV], (int)rr[2 * CONV + 1]), (int)rr[2 * CONV + 2]);
            int val = max(max(m0, m1), m2);
            p2i[n * F3 + (ocb + base + ol) * PP + pix] = (short)val;
            psum[q] = fmaxf((float)val + cb2[ocb + base + ol], 0.f);
        }
        __syncthreads();
        for (int ol = wv; ol < OCCHUNK; ol += 4) {
            float a = 0.f;
            for (int p = lane; p < PP; p += 64) a += psum[ol * PP + p];
            for (int off = 32; off; off >>= 1) a += __shfl_down(a, off);
            if (lane == 0) pm[base + ol] = a;
        }
        __syncthreads();
    }
    if (tid < OCH) part2[n * C2 + ocb + tid] = pm[tid];
}

// ---------------- p2 var partials ----------------
__global__ __launch_bounds__(256) void p2_var(const short* __restrict__ p2i,
                         const float* __restrict__ cb2,
                         const float* __restrict__ mean2, float* __restrict__ part) {
    int n = blockIdx.x, tid = threadIdx.x, lane = tid & 63, wv = tid >> 6;
    const short* rowb = p2i + (size_t)n * F3;
    __shared__ float red[C2];
#pragma unroll
    for (int i = 0; i < 16; i++) {
        int ch = wv * 16 + i;
        const short* row = rowb + ch * PP;
        float b = cb2[ch];
        float m = mean2[ch];
        float a = 0.f;
        for (int p = lane; p < PP; p += 64) {
            float v = fmaxf((float)row[p] + b, 0.f);
            float c = v - m;
            a += fabsf(c) * ap2mag(c);
        }
        for (int off = 32; off; off >>= 1) a += __shfl_down(a, off);
        if (lane == 0) red[ch] = a;
    }
    __syncthreads();
    if (tid < C2) part[n * C2 + tid] = red[tid];
}

// ---------------- stage-2 reduce: mean or ap2-scale ----------------
__global__ __launch_bounds__(256) void reduce_stats(const float* __restrict__ part, int nch, int nblk,
                             const float* __restrict__ g, float* __restrict__ outv,
                             int mode, double count) {
    int ch = blockIdx.x, tid = threadIdx.x;
    double a = 0.0;
    for (int i = tid; i < nblk; i += 256) a += (double)part[(size_t)i * nch + ch];
    __shared__ double red[4];
    for (int off = 32; off; off >>= 1) a += __shfl_down(a, off);
    int lane = tid & 63, wv = tid >> 6;
    if (lane == 0) red[wv] = a;
    __syncthreads();
    if (tid == 0) {
        double s = red[0] + red[1] + red[2] + red[3];
        if (mode == 0) {
            outv[ch] = (float)(s / count);
        } else {
            float var = (float)(s / count);
            float inv = 1.0f / sqrtf(var + 1e-4f);
            outv[ch] = ap2sgn(g[ch]) * ap2mag(inv);
        }
    }
}

// binarize layer-2 -> i8 (+1/-1) plane [BB][F3] for MFMA lin3
__global__ __launch_bounds__(256) void p2_packi8(const short* __restrict__ p2i, const float* __restrict__ cb2,
                        const float* __restrict__ mean2, const float* __restrict__ scale2,
                        const float* __restrict__ beta2, char* __restrict__ hp3i) {
    int idx = blockIdx.x * 256 + threadIdx.x;
    int nthr = gridDim.x * 256;
    int total = (BB * F3) / 4;
    for (int t = idx; t < total; t += nthr) {
        int base = t * 4;
        int f0 = base % F3;
        unsigned int w = 0;
#pragma unroll
        for (int e = 0; e < 4; e++) {
            int f = f0 + e;
            int oc = f / PP;
            float v = fmaxf((float)p2i[base + e] + cb2[oc], 0.f);
            float val = scale2[oc] * (v - mean2[oc]) + beta2[oc];
            w |= (val >= 0.f ? 0x01u : 0xffu) << (8 * e);
        }
        *(unsigned int*)(hp3i + base) = w;
    }
}

// ---------------- lin3: i8 MFMA GEMM, 128x128 block tile ----------------
// A = hp3i [M=2048][K=10816] i8 +-1, B = wp3i [N=2048][K]. K-chunk 64 = one
// mfma_i32_16x16x64_i8 step. 4 waves in 2x2; each wave 4x4 16x16 tiles (64x64).
// LDS holds tiles in FRAGMENT order (lane-linear ds_read_b128, conflict-free).
// k-permutation inside a fragment is irrelevant: same layout for A and B means
// any HW k-permutation cancels in the dot product. C/D map (col=lane&15,
// row=quad*4+reg) is the HW-verified mapping. Epilogue: bias+relu -> h3 and
// per-block column sums -> part3 (h3 mean partials).
__global__ __launch_bounds__(256) void lin3_mfma(const char* __restrict__ hp3i,
                                                 const char* __restrict__ wp3i,
                                                 const float* __restrict__ b3l,
                                                 float* __restrict__ h3,
                                                 float* __restrict__ part3) {
    __shared__ v4i aL[8 * 64];   // 8 KB: 8 rowgroups(16 rows) x 64 lane-frags
    __shared__ v4i bL[8 * 64];   // 8 KB
    __shared__ float csr[4][64];
    int tid = threadIdx.x;
    int lane = tid & 63, wv = tid >> 6;
    int wr = wv >> 1, wc = wv & 1;
    int m0 = blockIdx.y * 128, n0 = blockIdx.x * 128;
    // staging: thread t owns row r = t>>1 (of both A and B tiles), 32B half h
    int r = tid >> 1, h = tid & 1;
    const char* ag = hp3i + (size_t)(m0 + r) * F3 + h * 32;
    const char* bg = wp3i + (size_t)(n0 + r) * F3 + h * 32;
    int wbase = (r >> 4) * 64 + (2 * h) * 16 + (r & 15);  // frag-lane index for q=2h
    v4i acc[4][4];
#pragma unroll
    for (int i = 0; i < 4; i++)
#pragma unroll
        for (int j = 0; j < 4; j++) acc[i][j] = (v4i){0, 0, 0, 0};
    // prefetch chunk 0
    v4i a0 = *(const v4i*)ag, a1 = *(const v4i*)(ag + 16);
    v4i b0 = *(const v4i*)bg, b1 = *(const v4i*)(bg + 16);
    for (int c = 0; c < 169; c++) {
        __syncthreads();   // previous chunk's fragment reads complete
        aL[wbase] = a0; aL[wbase + 16] = a1;
        bL[wbase] = b0; bL[wbase + 16] = b1;
        __syncthreads();
        if (c < 168) {     // prefetch next chunk, overlaps MFMA below
            ag += 64; bg += 64;
            a0 = *(const v4i*)ag; a1 = *(const v4i*)(ag + 16);
            b0 = *(const v4i*)bg; b1 = *(const v4i*)(bg + 16);
        }
        v4i af[4], bf[4];
#pragma unroll
        for (int i = 0; i < 4; i++) af[i] = aL[(wr * 4 + i) * 64 + lane];
#pragma unroll
        for (int j = 0; j < 4; j++) bf[j] = bL[(wc * 4 + j) * 64 + lane];
#pragma unroll
        for (int i = 0; i < 4; i++)
#pragma unroll
            for (int j = 0; j < 4; j++)
                acc[i][j] = __builtin_amdgcn_mfma_i32_16x16x64_i8(af[i], bf[j], acc[i][j], 0, 0, 0);
    }
    int q = lane >> 4, m16 = lane & 15;
    float cs[4] = {0.f, 0.f, 0.f, 0.f};
#pragma unroll
    for (int j = 0; j < 4; j++) {
        int col = n0 + wc * 64 + j * 16 + m16;
        float bias = b3l[col];
#pragma unroll
        for (int i = 0; i < 4; i++) {
            int rowb = m0 + wr * 64 + i * 16 + q * 4;
#pragma unroll
            for (int rg = 0; rg < 4; rg++) {
                float v = fmaxf((float)acc[i][j][rg] + bias, 0.f);
                h3[(size_t)(rowb + rg) * N3 + col] = v;
                cs[j] += v;
            }
        }
    }
#pragma unroll
    for (int j = 0; j < 4; j++) {
        cs[j] += __shfl_xor(cs[j], 16);
        cs[j] += __shfl_xor(cs[j], 32);
        if (lane < 16) csr[wv][j * 16 + m16] = cs[j];
    }
    __syncthreads();
    if (tid < 128) {
        int wcc = tid >> 6, cc = tid & 63;
        part3[(size_t)blockIdx.y * N3 + n0 + wcc * 64 + cc] = csr[wcc][cc] + csr[wcc + 2][cc];
    }
}

// ---------------- h3: mean + var + scale, one kernel per column ----------------
__global__ __launch_bounds__(256) void h3_finish(const float* __restrict__ h3,
                                                 const float* __restrict__ part3,
                                                 const float* __restrict__ g3,
                                                 float* __restrict__ mean3, float* __restrict__ scale3) {
    int nn = blockIdx.x, tid = threadIdx.x;
    __shared__ float msh;
    __shared__ double redd[4];
    if (tid < 64) {
        float a = (tid < 16) ? part3[(size_t)tid * N3 + nn] : 0.f;
        for (int off = 8; off; off >>= 1) a += __shfl_down(a, off);
        if (tid == 0) { float m = a / (float)BB; mean3[nn] = m; msh = m; }
    }
    __syncthreads();
    float m = msh;
    float acc = 0.f;
#pragma unroll
    for (int q = 0; q < 8; q++) {
        float v = h3[(size_t)(q * 256 + tid) * N3 + nn];
        float c = v - m;
        acc += fabsf(c) * ap2mag(c);
    }
    double a = (double)acc;
    for (int off = 32; off; off >>= 1) a += __shfl_down(a, off);
    int lane = tid & 63, wv = tid >> 6;
    if (lane == 0) redd[wv] = a;
    __syncthreads();
    if (tid == 0) {
        float var = (float)((redd[0] + redd[1] + redd[2] + redd[3]) / (double)BB);
        float inv = 1.0f / sqrtf(var + 1e-4f);
        scale3[nn] = ap2sgn(g3[nn]) * ap2mag(inv);
    }
}

// ---------------- fused h3 binarize + lin4 (one block per sample) ----------------
__global__ __launch_bounds__(256) void h4_out(const float* __restrict__ h3,
                                              const float* __restrict__ mean3, const float* __restrict__ scale3,
                                              const float* __restrict__ bt3,
                                              const u64* __restrict__ wp4, const float* __restrict__ b4,
                                              float* __restrict__ out) {
    __shared__ u64 hb[K4W];
    __shared__ u64 wsh[NOUT * 33];
    int m = blockIdx.x, tid = threadIdx.x, lane = tid & 63, wv = tid >> 6;
    for (int i = tid; i < NOUT * K4W; i += 256) wsh[(i / K4W) * 33 + (i % K4W)] = wp4[i];
#pragma unroll
    for (int q = 0; q < 8; q++) {
        int j = wv * 8 + q;
        int f = j * 64 + lane;
        float v = h3[(size_t)m * N3 + f];
        float val = scale3[f] * (v - mean3[f]) + bt3[f];
        u64 mask = __ballot(val >= 0.f);
        if (lane == 0) hb[j] = mask;
    }
    __syncthreads();
    if (tid < NOUT) {
        int c = 0;
#pragma unroll
        for (int k = 0; k < K4W; k++) c += (int)__popcll(hb[k] ^ wsh[tid * 33 + k]);
        out[m * NOUT + tid] = (float)(N3 - 2 * c) + b4[tid];
    }
}

extern "C" void kernel_launch(void* const* d_in, const int* in_sizes, int n_in,
                              void* d_out, int out_size, void* d_ws, size_t ws_size,
                              hipStream_t stream) {
    const float* x   = (const float*)d_in[0];
    const float* w1  = (const float*)d_in[1];
    const float* cb1 = (const float*)d_in[2];
    const float* g1  = (const float*)d_in[3];
    const float* bt1 = (const float*)d_in[4];
    const float* w2  = (const float*)d_in[5];
    const float* cb2 = (const float*)d_in[6];
    const float* g2  = (const float*)d_in[7];
    const float* bt2 = (const float*)d_in[8];
    const float* w3  = (const float*)d_in[9];
    const float* b3l = (const float*)d_in[10];
    const float* g3  = (const float*)d_in[11];
    const float* bt3 = (const float*)d_in[12];
    const float* w4  = (const float*)d_in[13];
    const float* b4l = (const float*)d_in[14];
    float* out = (float*)d_out;

    char* base = (char*)d_ws;
    size_t off = 0;
    auto carve = [&](size_t bytes) { char* p = base + off; off = (off + bytes + 255) & ~(size_t)255; return p; };
    // lifetime-aliased buffers (keep total ~90 MB):
    char* bufA = carve((size_t)BB * C2 * PP * 2);   // p2i (44.3 MB); h3 aliases (dead after p2_packi8)
    char* bufB = carve((size_t)BB * F3);            // hp3i (22.2 MB); s1p aliases (dead before p2_packi8)
    char* bufC = carve((size_t)N3 * F3);            // wp3i (22.2 MB)
    short* p2i         = (short*)bufA;
    float* h3          = (float*)bufA;
    char* hp3i         = bufB;
    unsigned int* s1p  = (unsigned int*)bufB;
    char* wp3i         = bufC;
    u64* wp4           = (u64*)carve((size_t)NOUT * K4W * 8);
    unsigned int* w2p  = (unsigned int*)carve((size_t)C2 * 9 * 4);
    float* w1b         = (float*)carve((size_t)C1 * 9 * 4);
    float* part1       = (float*)carve((size_t)BB * C1 * 4);
    float* part2       = (float*)carve((size_t)BB * C2 * 4);
    float* part3       = (float*)carve((size_t)16 * N3 * 4);
    float* fstats      = (float*)carve((size_t)(32 + 32 + 64 + 64 + 2048 + 2048) * 4);
    float* mean1 = fstats;          float* scale1 = fstats + 32;
    float* mean2 = fstats + 64;     float* scale2 = fstats + 128;
    float* mean3 = fstats + 192;    float* scale3 = fstats + 2240;

    stage0<<<BB, 256, 0, stream>>>(x, w1, cb1, part1, w1b, w2, w2p, w3, wp3i, w4, wp4);
    reduce_stats<<<C1, 256, 0, stream>>>(part1, C1, BB, g1, mean1, 0, (double)BB * IMG);
    conv1_var<<<BB, 256, 0, stream>>>(x, w1b, cb1, mean1, part1);
    reduce_stats<<<C1, 256, 0, stream>>>(part1, C1, BB, g1, scale1, 1, (double)BB * IMG);
    conv1_pack<<<BB, 256, 0, stream>>>(x, w1b, cb1, mean1, scale1, bt1, s1p);
    conv2pool<<<dim3(BB, 2), 256, 0, stream>>>(s1p, w2p, cb2, p2i, part2);
    reduce_stats<<<C2, 256, 0, stream>>>(part2, C2, BB, g2, mean2, 0, (double)BB * PP);
    p2_var<<<BB, 256, 0, stream>>>(p2i, cb2, mean2, part2);
    reduce_stats<<<C2, 256, 0, stream>>>(part2, C2, BB, g2, scale2, 1, (double)BB * PP);
    p2_packi8<<<2048, 256, 0, stream>>>(p2i, cb2, mean2, scale2, bt2, hp3i);
    lin3_mfma<<<dim3(16, 16), 256, 0, stream>>>(hp3i, wp3i, b3l, h3, part3);
    h3_finish<<<N3, 256, 0, stream>>>(h3, part3, g3, mean3, scale3);
    h4_out<<<BB, 256, 0, stream>>>(h3, mean3, scale3, bt3, wp4, b4l, out);

    (void)in_sizes; (void)n_in; (void)out_size; (void)ws_size;
}

// Round 10
// 585.407 us; speedup vs baseline: 2.4515x; 1.0146x over previous
//
#include <hip/hip_runtime.h>

#define BB 2048
#define IMG 784
#define HWD 28
#define C1 32
#define C2 64
#define PP 169
#define PD 13
#define F3 10816
#define N3 2048
#define K4W 32
#define NOUT 10
#define CONV 27          // pooled-used conv2 output region is 27x27
#define PADW 30          // padded row stride (cols -1..28)
#define OCCHUNK 8
#define OCH 32           // ocs per conv2pool block (2 blocks per sample)
#define SCRS 736         // 729 padded

typedef unsigned long long u64;
typedef int v4i __attribute__((ext_vector_type(4)));

// ap2 magnitude, EXACT: 2^round(log2|c|). round crosses at mantissa sqrt(2).
__device__ __forceinline__ float ap2mag(float c) {
    unsigned int a = __float_as_uint(c) & 0x7fffffffu;
    unsigned int e = (a >> 23) + ((a & 0x7fffffu) > 0x3504f3u);
    return __uint_as_float(e << 23);
}
__device__ __forceinline__ float ap2sgn(float g) {
    unsigned int u = __float_as_uint(g);
    unsigned int a = u & 0x7fffffffu;
    if (a == 0) return 0.f;
    unsigned int e = (a >> 23) + ((a & 0x7fffffu) > 0x3504f3u);
    return __uint_as_float((u & 0x80000000u) | (e << 23));
}

// ---------------- stage0: conv1 mean partials + ALL weight packing ----------------
__global__ __launch_bounds__(256) void stage0(const float* __restrict__ x,
                                              const float* __restrict__ w1, const float* __restrict__ cb1,
                                              float* __restrict__ part1, float* __restrict__ w1b,
                                              const float* __restrict__ w2, unsigned int* __restrict__ w2p,
                                              const float* __restrict__ w3, char* __restrict__ wp3i,
                                              const float* __restrict__ w4, u64* __restrict__ wp4) {
    __shared__ float xs[30 * PADW];
    __shared__ float red[4 * C1];
    int n = blockIdx.x, tid = threadIdx.x;
    int lane = tid & 63, wv = tid >> 6;
    // w3 -> i8 (grid-stride over float4 groups)
    {
        int idx = n * 256 + tid;
        int nthr = gridDim.x * 256;
        int total = (N3 * F3) / 4;
        for (int t = idx; t < total; t += nthr) {
            float4 wv4 = *(const float4*)(w3 + (size_t)t * 4);
            unsigned int w = (wv4.x >= 0.f ? 0x01u : 0xffu)
                           | (wv4.y >= 0.f ? 0x01u : 0xffu) << 8
                           | (wv4.z >= 0.f ? 0x01u : 0xffu) << 16
                           | (wv4.w >= 0.f ? 0x01u : 0xffu) << 24;
            *(unsigned int*)(wp3i + (size_t)t * 4) = w;
        }
    }
    if (n == 0) {
        for (int i = tid; i < C1 * 9; i += 256) w1b[i] = (w1[i] >= 0.f) ? 1.f : -1.f;
    } else if (n == 1) {
        for (int t = tid; t < C2 * 9; t += 256) {
            int oc = t / 9, k = t % 9;
            unsigned int bits = 0;
            for (int ic = 0; ic < C1; ic++)
                bits |= (w2[oc * 288 + ic * 9 + k] >= 0.f ? 1u : 0u) << ic;
            w2p[t] = bits;
        }
    } else if (n == 2) {
        for (int w = wv; w < NOUT * K4W; w += 4) {
            int o = w / K4W, j = w % K4W;
            float wvl = w4[o * N3 + j * 64 + lane];
            u64 mask = __ballot(wvl >= 0.f);
            if (lane == 0) wp4[w] = mask;
        }
    }
    // conv1 pass0 (mean partials)
    for (int i = tid; i < 30 * PADW; i += 256) {
        int r = i / PADW - 1, c = i % PADW - 1;
        float v = 0.f;
        if (r >= 0 && r < HWD && c >= 0 && c < HWD) v = x[n * IMG + r * HWD + c];
        xs[i] = v;
    }
    __syncthreads();
    bool act = tid < 196;
    int r = tid / 7, c0 = (tid % 7) * 4;
    float win[18];
#pragma unroll
    for (int k = 0; k < 18; k++) win[k] = 0.f;
    if (act) {
#pragma unroll
        for (int ry = 0; ry < 3; ry++)
#pragma unroll
            for (int cx = 0; cx < 6; cx++)
                win[ry * 6 + cx] = xs[(r + ry) * PADW + c0 + cx];
    }
#pragma unroll
    for (int ch = 0; ch < C1; ch++) {
        float a = 0.f;
        if (act) {
            float k0 = (w1[ch * 9 + 0] >= 0.f) ? 1.f : -1.f, k1 = (w1[ch * 9 + 1] >= 0.f) ? 1.f : -1.f;
            float k2 = (w1[ch * 9 + 2] >= 0.f) ? 1.f : -1.f, k3 = (w1[ch * 9 + 3] >= 0.f) ? 1.f : -1.f;
            float k4 = (w1[ch * 9 + 4] >= 0.f) ? 1.f : -1.f, k5 = (w1[ch * 9 + 5] >= 0.f) ? 1.f : -1.f;
            float k6 = (w1[ch * 9 + 6] >= 0.f) ? 1.f : -1.f, k7 = (w1[ch * 9 + 7] >= 0.f) ? 1.f : -1.f;
            float k8 = (w1[ch * 9 + 8] >= 0.f) ? 1.f : -1.f;
            float b = cb1[ch];
#pragma unroll
            for (int px = 0; px < 4; px++) {
                float s = win[px] * k0 + win[px + 1] * k1 + win[px + 2] * k2
                        + win[6 + px] * k3 + win[7 + px] * k4 + win[8 + px] * k5
                        + win[12 + px] * k6 + win[13 + px] * k7 + win[14 + px] * k8;
                a += fmaxf(s + b, 0.f);
            }
        }
        for (int off = 32; off; off >>= 1) a += __shfl_down(a, off);
        if (lane == 0) red[wv * C1 + ch] = a;
    }
    __syncthreads();
    if (tid < C1) part1[n * C1 + tid] = red[tid] + red[C1 + tid] + red[2 * C1 + tid] + red[3 * C1 + tid];
}

// ---------------- conv1 var partials ----------------
__global__ __launch_bounds__(256) void conv1_var(const float* __restrict__ x,
                            const float* __restrict__ w1b,
                            const float* __restrict__ cb1, const float* __restrict__ mean1,
                            float* __restrict__ part) {
    __shared__ float xs[30 * PADW];
    __shared__ float red[4 * C1];
    int n = blockIdx.x, tid = threadIdx.x;
    for (int i = tid; i < 30 * PADW; i += 256) {
        int r = i / PADW - 1, c = i % PADW - 1;
        float v = 0.f;
        if (r >= 0 && r < HWD && c >= 0 && c < HWD) v = x[n * IMG + r * HWD + c];
        xs[i] = v;
    }
    __syncthreads();
    bool act = tid < 196;
    int r = tid / 7, c0 = (tid % 7) * 4;
    float win[18];
#pragma unroll
    for (int k = 0; k < 18; k++) win[k] = 0.f;
    if (act) {
#pragma unroll
        for (int ry = 0; ry < 3; ry++)
#pragma unroll
            for (int cx = 0; cx < 6; cx++)
                win[ry * 6 + cx] = xs[(r + ry) * PADW + c0 + cx];
    }
    int lane = tid & 63, wv = tid >> 6;
#pragma unroll
    for (int ch = 0; ch < C1; ch++) {
        float a = 0.f;
        if (act) {
            float k0 = w1b[ch * 9 + 0], k1 = w1b[ch * 9 + 1], k2 = w1b[ch * 9 + 2];
            float k3 = w1b[ch * 9 + 3], k4 = w1b[ch * 9 + 4], k5 = w1b[ch * 9 + 5];
            float k6 = w1b[ch * 9 + 6], k7 = w1b[ch * 9 + 7], k8 = w1b[ch * 9 + 8];
            float b = cb1[ch], m = mean1[ch];
#pragma unroll
            for (int px = 0; px < 4; px++) {
                float s = win[px] * k0 + win[px + 1] * k1 + win[px + 2] * k2
                        + win[6 + px] * k3 + win[7 + px] * k4 + win[8 + px] * k5
                        + win[12 + px] * k6 + win[13 + px] * k7 + win[14 + px] * k8;
                float v = fmaxf(s + b, 0.f);
                float c = v - m;
                a += fabsf(c) * ap2mag(c);
            }
        }
        for (int off = 32; off; off >>= 1) a += __shfl_down(a, off);
        if (lane == 0) red[wv * C1 + ch] = a;
    }
    __syncthreads();
    if (tid < C1) part[n * C1 + tid] = red[tid] + red[C1 + tid] + red[2 * C1 + tid] + red[3 * C1 + tid];
}

// binarize(shift_bn(relu(conv1))) -> 32 channel bits per pixel, aligned uint4 store.
__global__ __launch_bounds__(256) void conv1_pack(const float* __restrict__ x,
                           const float* __restrict__ w1b,
                           const float* __restrict__ cb1, const float* __restrict__ mean1,
                           const float* __restrict__ scale1, const float* __restrict__ beta1,
                           unsigned int* __restrict__ s1p) {
    __shared__ float xs[30 * PADW];
    int n = blockIdx.x, tid = threadIdx.x;
    for (int i = tid; i < 30 * PADW; i += 256) {
        int r = i / PADW - 1, c = i % PADW - 1;
        float v = 0.f;
        if (r >= 0 && r < HWD && c >= 0 && c < HWD) v = x[n * IMG + r * HWD + c];
        xs[i] = v;
    }
    __syncthreads();
    if (tid >= 196) return;
    int r = tid / 7, c0 = (tid % 7) * 4;
    float win[18];
#pragma unroll
    for (int ry = 0; ry < 3; ry++)
#pragma unroll
        for (int cx = 0; cx < 6; cx++)
            win[ry * 6 + cx] = xs[(r + ry) * PADW + c0 + cx];
    unsigned int bits0 = 0, bits1 = 0, bits2 = 0, bits3 = 0;
#pragma unroll
    for (int ch = 0; ch < C1; ch++) {
        float k0 = w1b[ch * 9 + 0], k1 = w1b[ch * 9 + 1], k2 = w1b[ch * 9 + 2];
        float k3 = w1b[ch * 9 + 3], k4 = w1b[ch * 9 + 4], k5 = w1b[ch * 9 + 5];
        float k6 = w1b[ch * 9 + 6], k7 = w1b[ch * 9 + 7], k8 = w1b[ch * 9 + 8];
        float b = cb1[ch], m = mean1[ch], sc = scale1[ch], bt = beta1[ch];
#pragma unroll
        for (int px = 0; px < 4; px++) {
            float s = win[px] * k0 + win[px + 1] * k1 + win[px + 2] * k2
                    + win[6 + px] * k3 + win[7 + px] * k4 + win[8 + px] * k5
                    + win[12 + px] * k6 + win[13 + px] * k7 + win[14 + px] * k8;
            float v = fmaxf(s + b, 0.f);
            float val = sc * (v - m) + bt;
            unsigned int bit = (val >= 0.f ? 1u : 0u) << ch;
            if (px == 0) bits0 |= bit;
            else if (px == 1) bits1 |= bit;
            else if (px == 2) bits2 |= bit;
            else bits3 |= bit;
        }
    }
    uint4 w4v = make_uint4(bits0, bits1, bits2, bits3);
    *reinterpret_cast<uint4*>(&s1p[n * IMG + r * HWD + c0]) = w4v;  // 16B aligned
}

// ---------------- conv2 + maxpool3s2 + mean partials, 2 blocks/sample ----------------
__global__ __launch_bounds__(256) void conv2pool(const unsigned int* __restrict__ s1p,
                                                 const unsigned int* __restrict__ w2p,
                                                 const float* __restrict__ cb2,
                                                 short* __restrict__ p2i,
                                                 float* __restrict__ part2) {
    __shared__ unsigned int spad[29 * PADW];   // 3.5 KB
    __shared__ short scr[OCCHUNK * SCRS];      // 11.8 KB
    __shared__ float psum[OCCHUNK * PP];       // 5.4 KB
    __shared__ float pm[OCH];
    int n = blockIdx.x, ocb = blockIdx.y * OCH, tid = threadIdx.x;
    for (int i = tid; i < 29 * PADW; i += 256) {
        int r = i / PADW, c = i - r * PADW;
        unsigned int v = 0;
        if (r >= 1 && c >= 1 && c <= 28) v = s1p[n * IMG + (r - 1) * HWD + (c - 1)];
        spad[i] = v;
    }
    __syncthreads();
    unsigned int win[3][9];
    bool top_[3], left_[3];
    bool act2 = (tid + 512) < CONV * CONV;
#pragma unroll
    for (int pi = 0; pi < 3; pi++) {
        int p = tid + pi * 256;
        if (p >= CONV * CONV) p = 0;
        int y = p / CONV, xx = p - y * CONV;
        top_[pi] = (y == 0);
        left_[pi] = (xx == 0);
        const unsigned int* bp = &spad[y * PADW + xx];
#pragma unroll
        for (int ky = 0; ky < 3; ky++)
#pragma unroll
            for (int kx = 0; kx < 3; kx++)
                win[pi][ky * 3 + kx] = bp[ky * PADW + kx];
    }
    int lane = tid & 63, wv = tid >> 6;
    for (int base = 0; base < OCH; base += OCCHUNK) {
        for (int ol = 0; ol < OCCHUNK; ol++) {
            int oc = ocb + base + ol;
            unsigned int w0 = w2p[oc * 9 + 0], w1 = w2p[oc * 9 + 1], w2 = w2p[oc * 9 + 2];
            unsigned int w3 = w2p[oc * 9 + 3], w4 = w2p[oc * 9 + 4], w5 = w2p[oc * 9 + 5];
            unsigned int w6 = w2p[oc * 9 + 6], w7 = w2p[oc * 9 + 7], w8 = w2p[oc * 9 + 8];
            int p0 = __popc(w0), p1 = __popc(w1), p2 = __popc(w2);
            int p3 = __popc(w3), p6 = __popc(w6);
            int ct = 192 + 2 * (p0 + p1 + p2);
            int cl = 192 + 2 * (p0 + p3 + p6);
            int cc = 128 + 2 * (p0 + p1 + p2 + p3 + p6);
#pragma unroll
            for (int pi = 0; pi < 3; pi++) {
                int s = __popc(win[pi][0] ^ w0) + __popc(win[pi][1] ^ w1) + __popc(win[pi][2] ^ w2)
                      + __popc(win[pi][3] ^ w3) + __popc(win[pi][4] ^ w4) + __popc(win[pi][5] ^ w5)
                      + __popc(win[pi][6] ^ w6) + __popc(win[pi][7] ^ w7) + __popc(win[pi][8] ^ w8);
                int off = top_[pi] ? (left_[pi] ? cc : ct) : (left_[pi] ? cl : 288);
                if (pi < 2 || act2) scr[ol * SCRS + tid + pi * 256] = (short)(off - 2 * s);
            }
        }
        __syncthreads();
        for (int q = tid; q < OCCHUNK * PP; q += 256) {
            int ol = q / PP, pix = q - ol * PP;
            int py = pix / PD, px = pix - py * PD;
            const short* rr = &scr[ol * SCRS + (2 * py) * CONV + 2 * px];
            int m0 = max(max((int)rr[0], (int)rr[1]), (int)rr[2]);
            int m1 = max(max((int)rr[CONV], (int)rr[CONV + 1]), (int)rr[CONV + 2]);
            int m2 = max(max((int)rr[2 * CONV], (int)rr[2 * CONV + 1]), (int)rr[2 * CONV + 2]);
            int val = max(max(m0, m1), m2);
            p2i[n * F3 + (ocb + base + ol) * PP + pix] = (short)val;
            psum[q] = fmaxf((float)val + cb2[ocb + base + ol], 0.f);
        }
        __syncthreads();
        for (int ol = wv; ol < OCCHUNK; ol += 4) {
            float a = 0.f;
            for (int p = lane; p < PP; p += 64) a += psum[ol * PP + p];
            for (int off = 32; off; off >>= 1) a += __shfl_down(a, off);
            if (lane == 0) pm[base + ol] = a;
        }
        __syncthreads();
    }
    if (tid < OCH) part2[n * C2 + ocb + tid] = pm[tid];
}

// ---------------- p2 var partials ----------------
__global__ __launch_bounds__(256) void p2_var(const short* __restrict__ p2i,
                         const float* __restrict__ cb2,
                         const float* __restrict__ mean2, float* __restrict__ part) {
    int n = blockIdx.x, tid = threadIdx.x, lane = tid & 63, wv = tid >> 6;
    const short* rowb = p2i + (size_t)n * F3;
    __shared__ float red[C2];
#pragma unroll
    for (int i = 0; i < 16; i++) {
        int ch = wv * 16 + i;
        const short* row = rowb + ch * PP;
        float b = cb2[ch];
        float m = mean2[ch];
        float a = 0.f;
        for (int p = lane; p < PP; p += 64) {
            float v = fmaxf((float)row[p] + b, 0.f);
            float c = v - m;
            a += fabsf(c) * ap2mag(c);
        }
        for (int off = 32; off; off >>= 1) a += __shfl_down(a, off);
        if (lane == 0) red[ch] = a;
    }
    __syncthreads();
    if (tid < C2) part[n * C2 + tid] = red[tid];
}

// ---------------- stage-2 reduce: mean or ap2-scale ----------------
__global__ __launch_bounds__(256) void reduce_stats(const float* __restrict__ part, int nch, int nblk,
                             const float* __restrict__ g, float* __restrict__ outv,
                             int mode, double count) {
    int ch = blockIdx.x, tid = threadIdx.x;
    double a = 0.0;
    for (int i = tid; i < nblk; i += 256) a += (double)part[(size_t)i * nch + ch];
    __shared__ double red[4];
    for (int off = 32; off; off >>= 1) a += __shfl_down(a, off);
    int lane = tid & 63, wv = tid >> 6;
    if (lane == 0) red[wv] = a;
    __syncthreads();
    if (tid == 0) {
        double s = red[0] + red[1] + red[2] + red[3];
        if (mode == 0) {
            outv[ch] = (float)(s / count);
        } else {
            float var = (float)(s / count);
            float inv = 1.0f / sqrtf(var + 1e-4f);
            outv[ch] = ap2sgn(g[ch]) * ap2mag(inv);
        }
    }
}

// binarize layer-2 -> i8 (+1/-1) plane [BB][F3] for MFMA lin3
__global__ __launch_bounds__(256) void p2_packi8(const short* __restrict__ p2i, const float* __restrict__ cb2,
                        const float* __restrict__ mean2, const float* __restrict__ scale2,
                        const float* __restrict__ beta2, char* __restrict__ hp3i) {
    int idx = blockIdx.x * 256 + threadIdx.x;
    int nthr = gridDim.x * 256;
    int total = (BB * F3) / 4;
    for (int t = idx; t < total; t += nthr) {
        int base = t * 4;
        int f0 = base % F3;
        unsigned int w = 0;
#pragma unroll
        for (int e = 0; e < 4; e++) {
            int f = f0 + e;
            int oc = f / PP;
            float v = fmaxf((float)p2i[base + e] + cb2[oc], 0.f);
            float val = scale2[oc] * (v - mean2[oc]) + beta2[oc];
            w |= (val >= 0.f ? 0x01u : 0xffu) << (8 * e);
        }
        *(unsigned int*)(hp3i + base) = w;
    }
}

// ---------------- lin3: i8 MFMA GEMM, 128x64 tile, double-buffered LDS ----------------
// R9 post-mortem: grid 256 = 1 block/CU (4 waves) -> every chunk's vmcnt(0) stalled
// the whole CU (Occupancy 10.6%, MfmaUtil 15%). Fix: 512 blocks (2 blocks/CU) +
// LDS double-buffer with ONE barrier per chunk. Wave tile 64x32 (4x2 MFMA tiles).
// k-permutation inside fragments cancels (same layout both operands); C/D map
// col=lane&15, row=(lane>>4)*4+reg (HW-verified).
__global__ __launch_bounds__(256) void lin3_mfma(const char* __restrict__ hp3i,
                                                 const char* __restrict__ wp3i,
                                                 const float* __restrict__ b3l,
                                                 float* __restrict__ h3,
                                                 float* __restrict__ part3) {
    __shared__ v4i aL[2][512];   // 2 bufs x (8 rowgroups x 64 lane-frags) = 16 KB
    __shared__ v4i bL[2][256];   // 2 bufs x (4 rowgroups x 64) = 8 KB
    __shared__ float csr[4][32];
    int tid = threadIdx.x;
    int lane = tid & 63, wv = tid >> 6;
    int wr = wv >> 1, wc = wv & 1;
    int m0 = blockIdx.y * 128, n0 = blockIdx.x * 64;
    // A staging: thread t owns row ra = t>>1, 32B half ha = t&1
    int ra = tid >> 1, ha = tid & 1;
    const char* ag = hp3i + (size_t)(m0 + ra) * F3 + ha * 32;
    int abase = (ra >> 4) * 64 + (2 * ha) * 16 + (ra & 15);
    // B staging: thread t owns row rb = t>>2, 16B quarter qb = t&3
    int rb = tid >> 2, qb = tid & 3;
    const char* bg = wp3i + (size_t)(n0 + rb) * F3 + qb * 16;
    int bbase = (rb >> 4) * 64 + qb * 16 + (rb & 15);
    v4i acc[4][2];
#pragma unroll
    for (int i = 0; i < 4; i++)
#pragma unroll
        for (int j = 0; j < 2; j++) acc[i][j] = (v4i){0, 0, 0, 0};
    // preload chunk 0 into buf 0
    v4i a0 = *(const v4i*)ag, a1 = *(const v4i*)(ag + 16);
    v4i b0 = *(const v4i*)bg;
    aL[0][abase] = a0; aL[0][abase + 16] = a1;
    bL[0][bbase] = b0;
    __syncthreads();
    for (int c = 0; c < 169; c++) {
        int cur = c & 1, nxt = cur ^ 1;
        if (c < 168) {  // issue prefetch of next chunk (overlaps MFMA below)
            ag += 64; bg += 64;
            a0 = *(const v4i*)ag; a1 = *(const v4i*)(ag + 16);
            b0 = *(const v4i*)bg;
        }
        v4i af[4], bf[2];
#pragma unroll
        for (int i = 0; i < 4; i++) af[i] = aL[cur][(wr * 4 + i) * 64 + lane];
#pragma unroll
        for (int j = 0; j < 2; j++) bf[j] = bL[cur][(wc * 2 + j) * 64 + lane];
#pragma unroll
        for (int i = 0; i < 4; i++)
#pragma unroll
            for (int j = 0; j < 2; j++)
                acc[i][j] = __builtin_amdgcn_mfma_i32_16x16x64_i8(af[i], bf[j], acc[i][j], 0, 0, 0);
        if (c < 168) {  // store prefetch into the other buffer
            aL[nxt][abase] = a0; aL[nxt][abase + 16] = a1;
            bL[nxt][bbase] = b0;
        }
        __syncthreads();
    }
    int q = lane >> 4, m16 = lane & 15;
    float cs[2] = {0.f, 0.f};
#pragma unroll
    for (int j = 0; j < 2; j++) {
        int col = n0 + wc * 32 + j * 16 + m16;
        float bias = b3l[col];
#pragma unroll
        for (int i = 0; i < 4; i++) {
            int rowb = m0 + wr * 64 + i * 16 + q * 4;
#pragma unroll
            for (int rg = 0; rg < 4; rg++) {
                float v = fmaxf((float)acc[i][j][rg] + bias, 0.f);
                h3[(size_t)(rowb + rg) * N3 + col] = v;
                cs[j] += v;
            }
        }
    }
#pragma unroll
    for (int j = 0; j < 2; j++) {
        cs[j] += __shfl_xor(cs[j], 16);
        cs[j] += __shfl_xor(cs[j], 32);
        if (lane < 16) csr[wv][j * 16 + m16] = cs[j];
    }
    __syncthreads();
    if (tid < 64) {
        int wcc = tid >> 5, cc = tid & 31;   // column group, index
        part3[(size_t)blockIdx.y * N3 + n0 + tid] = csr[wcc][cc] + csr[2 + wcc][cc];
    }
}

// ---------------- h3: mean + var + scale, one kernel per column ----------------
__global__ __launch_bounds__(256) void h3_finish(const float* __restrict__ h3,
                                                 const float* __restrict__ part3,
                                                 const float* __restrict__ g3,
                                                 float* __restrict__ mean3, float* __restrict__ scale3) {
    int nn = blockIdx.x, tid = threadIdx.x;
    __shared__ float msh;
    __shared__ double redd[4];
    if (tid < 64) {
        float a = (tid < 16) ? part3[(size_t)tid * N3 + nn] : 0.f;
        for (int off = 8; off; off >>= 1) a += __shfl_down(a, off);
        if (tid == 0) { float m = a / (float)BB; mean3[nn] = m; msh = m; }
    }
    __syncthreads();
    float m = msh;
    float acc = 0.f;
#pragma unroll
    for (int q = 0; q < 8; q++) {
        float v = h3[(size_t)(q * 256 + tid) * N3 + nn];
        float c = v - m;
        acc += fabsf(c) * ap2mag(c);
    }
    double a = (double)acc;
    for (int off = 32; off; off >>= 1) a += __shfl_down(a, off);
    int lane = tid & 63, wv = tid >> 6;
    if (lane == 0) redd[wv] = a;
    __syncthreads();
    if (tid == 0) {
        float var = (float)((redd[0] + redd[1] + redd[2] + redd[3]) / (double)BB);
        float inv = 1.0f / sqrtf(var + 1e-4f);
        scale3[nn] = ap2sgn(g3[nn]) * ap2mag(inv);
    }
}

// ---------------- fused h3 binarize + lin4 (one block per sample) ----------------
__global__ __launch_bounds__(256) void h4_out(const float* __restrict__ h3,
                                              const float* __restrict__ mean3, const float* __restrict__ scale3,
                                              const float* __restrict__ bt3,
                                              const u64* __restrict__ wp4, const float* __restrict__ b4,
                                              float* __restrict__ out) {
    __shared__ u64 hb[K4W];
    __shared__ u64 wsh[NOUT * 33];
    int m = blockIdx.x, tid = threadIdx.x, lane = tid & 63, wv = tid >> 6;
    for (int i = tid; i < NOUT * K4W; i += 256) wsh[(i / K4W) * 33 + (i % K4W)] = wp4[i];
#pragma unroll
    for (int q = 0; q < 8; q++) {
        int j = wv * 8 + q;
        int f = j * 64 + lane;
        float v = h3[(size_t)m * N3 + f];
        float val = scale3[f] * (v - mean3[f]) + bt3[f];
        u64 mask = __ballot(val >= 0.f);
        if (lane == 0) hb[j] = mask;
    }
    __syncthreads();
    if (tid < NOUT) {
        int c = 0;
#pragma unroll
        for (int k = 0; k < K4W; k++) c += (int)__popcll(hb[k] ^ wsh[tid * 33 + k]);
        out[m * NOUT + tid] = (float)(N3 - 2 * c) + b4[tid];
    }
}

extern "C" void kernel_launch(void* const* d_in, const int* in_sizes, int n_in,
                              void* d_out, int out_size, void* d_ws, size_t ws_size,
                              hipStream_t stream) {
    const float* x   = (const float*)d_in[0];
    const float* w1  = (const float*)d_in[1];
    const float* cb1 = (const float*)d_in[2];
    const float* g1  = (const float*)d_in[3];
    const float* bt1 = (const float*)d_in[4];
    const float* w2  = (const float*)d_in[5];
    const float* cb2 = (const float*)d_in[6];
    const float* g2  = (const float*)d_in[7];
    const float* bt2 = (const float*)d_in[8];
    const float* w3  = (const float*)d_in[9];
    const float* b3l = (const float*)d_in[10];
    const float* g3  = (const float*)d_in[11];
    const float* bt3 = (const float*)d_in[12];
    const float* w4  = (const float*)d_in[13];
    const float* b4l = (const float*)d_in[14];
    float* out = (float*)d_out;

    char* base = (char*)d_ws;
    size_t off = 0;
    auto carve = [&](size_t bytes) { char* p = base + off; off = (off + bytes + 255) & ~(size_t)255; return p; };
    // lifetime-aliased buffers:
    char* bufA = carve((size_t)BB * C2 * PP * 2);   // p2i (44.3 MB); h3 aliases (dead after p2_packi8)
    char* bufB = carve((size_t)BB * F3);            // hp3i (22.2 MB); s1p aliases (dead before p2_packi8)
    char* bufC = carve((size_t)N3 * F3);            // wp3i (22.2 MB)
    short* p2i         = (short*)bufA;
    float* h3          = (float*)bufA;
    char* hp3i         = bufB;
    unsigned int* s1p  = (unsigned int*)bufB;
    char* wp3i         = bufC;
    u64* wp4           = (u64*)carve((size_t)NOUT * K4W * 8);
    unsigned int* w2p  = (unsigned int*)carve((size_t)C2 * 9 * 4);
    float* w1b         = (float*)carve((size_t)C1 * 9 * 4);
    float* part1       = (float*)carve((size_t)BB * C1 * 4);
    float* part2       = (float*)carve((size_t)BB * C2 * 4);
    float* part3       = (float*)carve((size_t)16 * N3 * 4);
    float* fstats      = (float*)carve((size_t)(32 + 32 + 64 + 64 + 2048 + 2048) * 4);
    float* mean1 = fstats;          float* scale1 = fstats + 32;
    float* mean2 = fstats + 64;     float* scale2 = fstats + 128;
    float* mean3 = fstats + 192;    float* scale3 = fstats + 2240;

    stage0<<<BB, 256, 0, stream>>>(x, w1, cb1, part1, w1b, w2, w2p, w3, wp3i, w4, wp4);
    reduce_stats<<<C1, 256, 0, stream>>>(part1, C1, BB, g1, mean1, 0, (double)BB * IMG);
    conv1_var<<<BB, 256, 0, stream>>>(x, w1b, cb1, mean1, part1);
    reduce_stats<<<C1, 256, 0, stream>>>(part1, C1, BB, g1, scale1, 1, (double)BB * IMG);
    conv1_pack<<<BB, 256, 0, stream>>>(x, w1b, cb1, mean1, scale1, bt1, s1p);
    conv2pool<<<dim3(BB, 2), 256, 0, stream>>>(s1p, w2p, cb2, p2i, part2);
    reduce_stats<<<C2, 256, 0, stream>>>(part2, C2, BB, g2, mean2, 0, (double)BB * PP);
    p2_var<<<BB, 256, 0, stream>>>(p2i, cb2, mean2, part2);
    reduce_stats<<<C2, 256, 0, stream>>>(part2, C2, BB, g2, scale2, 1, (double)BB * PP);
    p2_packi8<<<2048, 256, 0, stream>>>(p2i, cb2, mean2, scale2, bt2, hp3i);
    lin3_mfma<<<dim3(32, 16), 256, 0, stream>>>(hp3i, wp3i, b3l, h3, part3);
    h3_finish<<<N3, 256, 0, stream>>>(h3, part3, g3, mean3, scale3);
    h4_out<<<BB, 256, 0, stream>>>(h3, mean3, scale3, bt3, wp4, b4l, out);

    (void)in_sizes; (void)n_in; (void)out_size; (void)ws_size;
}